// Round 4
// baseline (264.265 us; speedup 1.0000x reference)
//
#include <hip/hip_runtime.h>
#include <hip/hip_bf16.h>

typedef __attribute__((ext_vector_type(8))) short bf16x8;
typedef __attribute__((ext_vector_type(4))) float f32x4;
typedef __attribute__((ext_vector_type(4))) unsigned short u16x4;

__device__ __forceinline__ unsigned short f2bf(float f) {
    union { float f; unsigned int i; } x; x.f = f;
    unsigned int lsb = (x.i >> 16) & 1u;
    x.i += 0x7fffu + lsb;  // round-to-nearest-even
    return (unsigned short)(x.i >> 16);
}

// async global->LDS DMA, 16B per lane; lds ptr wave-uniform, HW adds lane*16
__device__ __forceinline__ void gl_lds16(const unsigned short* g, unsigned short* l) {
    __builtin_amdgcn_global_load_lds(
        (const __attribute__((address_space(1))) void*)g,
        (__attribute__((address_space(3))) void*)l, 16, 0, 0);
}

__device__ __forceinline__ unsigned int cvt_pk_bf16(float lo, float hi) {
    unsigned int d;
    asm("v_cvt_pk_bf16_f32 %0, %1, %2" : "=v"(d) : "v"(lo), "v"(hi));
    return d;
}

// In-register 16x32 C-fragment transpose -> A-frag/store layout (attn-verified).
// Input: pa = C-frag rows 0..15 of a 32-row span (per-lane row=kg*4+r, col=ln15),
//        pb = rows 16..31. Output: lane (kg,ln15) holds bf16 of rows kg*8..kg*8+7
// at fixed col=ln15 -> one contiguous 16B run along the row direction.
__device__ __forceinline__ bf16x8 pf_build_s(f32x4 pa, f32x4 pb, float s) {
    unsigned int E0 = cvt_pk_bf16(pa[0] * s, pa[1] * s);
    unsigned int O0 = cvt_pk_bf16(pa[2] * s, pa[3] * s);
    unsigned int E1 = cvt_pk_bf16(pb[0] * s, pb[1] * s);
    unsigned int O1 = cvt_pk_bf16(pb[2] * s, pb[3] * s);
    asm("v_permlane32_swap_b32 %0, %1" : "+v"(E0), "+v"(E1));
    asm("v_permlane32_swap_b32 %0, %1" : "+v"(O0), "+v"(O1));
    asm("v_permlane16_swap_b32 %0, %1" : "+v"(E0), "+v"(E1));
    asm("v_permlane16_swap_b32 %0, %1" : "+v"(O0), "+v"(O1));
    union { unsigned int u[4]; bf16x8 v; } r;
    r.u[0] = E0; r.u[1] = O0; r.u[2] = E1; r.u[3] = O1;
    return r.v;
}

// ---------------------------------------------------------------------------
// fused preprocessing: blocks [0,4096) = fp32->bf16 convert of x (x4 vec);
// blocks [4096,8192) = 32x32 transpose+convert of the 4 weight matrices.
// ---------------------------------------------------------------------------
__global__ __launch_bounds__(256) void prep(
    const float* __restrict__ x,
    const float* __restrict__ Wq, const float* __restrict__ Wk,
    const float* __restrict__ Wv, const float* __restrict__ Wo,
    unsigned short* __restrict__ xb,
    unsigned short* __restrict__ WqkvT, unsigned short* __restrict__ WoT)
{
    const int E = 1024;
    const int bid = blockIdx.x;
    __shared__ float t[32][33];

    if (bid < 4096) {                       // x convert: 4096*256*4 = 4M elems
        int i = bid * 256 + threadIdx.x;
        f32x4 v = ((const f32x4*)x)[i];
        u16x4 o;
#pragma unroll
        for (int j = 0; j < 4; ++j) o[j] = f2bf(v[j]);
        ((u16x4*)xb)[i] = o;
        return;
    }
    const int r = bid - 4096;
    const int which = r >> 10;              // 0..3 : Wq,Wk,Wv,Wo
    const int sub = r & 1023;
    const float* src = which == 0 ? Wq : which == 1 ? Wk : which == 2 ? Wv : Wo;
    unsigned short* dst = which == 3 ? WoT : WqkvT + (size_t)which * E * E;

    const int tx = threadIdx.x & 31, ty = threadIdx.x >> 5;  // ty 0..7
    const int n0 = (sub & 31) * 32, k0 = (sub >> 5) * 32;
#pragma unroll
    for (int i = 0; i < 4; ++i)
        t[ty + 8 * i][tx] = src[(size_t)(k0 + ty + 8 * i) * E + n0 + tx];
    __syncthreads();
#pragma unroll
    for (int i = 0; i < 4; ++i)
        dst[(size_t)(n0 + ty + 8 * i) * E + k0 + tx] = f2bf(t[tx][ty + 8 * i]);
}

// ---------------------------------------------------------------------------
// m97-style GEMM: C = A[M,K] @ BT[N,K]^T, bf16 in, fp32 acc. 128x128 tile,
// BK=32, 256 thr = 4 waves 2x2; 16 MFMA + 8 ds_read_b128 per K-step/wave;
// staging via global_load_lds dwordx4.
//
// SINGLE-PATH main loop per template instantiation (round-2 lesson: a
// uniform-but-runtime swap branch around the MFMAs inside the K-loop cost
// 48% -- MfmaUtil 21.6->14.9, VGPR 72->92. PERM is compile-time, so each
// instantiation has exactly one MFMA ordering and no loop-body branches).
//
// PERM=1 (QKV): unswapped mfma(af,bw). Epilogue: q/k scalar u16 stores; the
// v section uses the in-register fragment transpose (pf_build) whose
// t-contiguous output writes V TRANSPOSED [bh][d][t] directly.
// PERM=0 (out-proj): swapped mfma(bw,af) = C^T frags (compile-time path),
// epilogue = f32x4 bias+store, fully vectorized.
// ---------------------------------------------------------------------------
template <int PERM>
__global__ __launch_bounds__(256) void gemm128(
    const unsigned short* __restrict__ A,
    const unsigned short* __restrict__ BT,
    const float* __restrict__ bias,
    float* __restrict__ Cf,
    unsigned short* __restrict__ q_out,
    unsigned short* __restrict__ k_out,
    unsigned short* __restrict__ v_out,   // [bh][64][T] transposed
    int M, int N, int K)
{
    __shared__ __align__(16) unsigned short As[128 * 32];
    __shared__ __align__(16) unsigned short Bs[128 * 32];

    const int tid  = threadIdx.x;
    const int wave = tid >> 6;
    const int lane = tid & 63;
    const int ln15 = lane & 15;
    const int kg   = lane >> 4;
    const int bm = blockIdx.x * 128, bn = blockIdx.y * 128;
    const int wm = (wave >> 1) * 64, wn = (wave & 1) * 64;

    f32x4 acc[4][4];
#pragma unroll
    for (int i = 0; i < 4; ++i)
#pragma unroll
        for (int j = 0; j < 4; ++j) acc[i][j] = (f32x4){0.f, 0.f, 0.f, 0.f};

    const int sr = wave * 32 + (lane >> 2);
    const int sc = (lane & 3) * 8;

    for (int k0 = 0; k0 < K; k0 += 32) {
        gl_lds16(A  + (size_t)(bm + sr)      * K + k0 + sc, As + wave * 1024);
        gl_lds16(A  + (size_t)(bm + sr + 16) * K + k0 + sc, As + wave * 1024 + 512);
        gl_lds16(BT + (size_t)(bn + sr)      * K + k0 + sc, Bs + wave * 1024);
        gl_lds16(BT + (size_t)(bn + sr + 16) * K + k0 + sc, Bs + wave * 1024 + 512);
        __syncthreads();

        bf16x8 af[4], bw[4];
#pragma unroll
        for (int mt = 0; mt < 4; ++mt)
            af[mt] = *(const bf16x8*)&As[(wm + mt * 16 + ln15) * 32 + kg * 8];
#pragma unroll
        for (int nt = 0; nt < 4; ++nt)
            bw[nt] = *(const bf16x8*)&Bs[(wn + nt * 16 + ln15) * 32 + kg * 8];
        if (PERM == 0) {   // compile-time: C^T fragments
#pragma unroll
            for (int mt = 0; mt < 4; ++mt)
#pragma unroll
                for (int nt = 0; nt < 4; ++nt)
                    acc[mt][nt] = __builtin_amdgcn_mfma_f32_16x16x32_bf16(
                        bw[nt], af[mt], acc[mt][nt], 0, 0, 0);
        } else {           // compile-time: C fragments
#pragma unroll
            for (int mt = 0; mt < 4; ++mt)
#pragma unroll
                for (int nt = 0; nt < 4; ++nt)
                    acc[mt][nt] = __builtin_amdgcn_mfma_f32_16x16x32_bf16(
                        af[mt], bw[nt], acc[mt][nt], 0, 0, 0);
        }
        __syncthreads();
    }

    if (PERM == 0) {
        // swapped: acc[mt][nt][r] = C[row=bm+wm+mt*16+ln15][col=bn+wn+nt*16+kg*4+r]
#pragma unroll
        for (int mt = 0; mt < 4; ++mt) {
            const int row = bm + wm + mt * 16 + ln15;
#pragma unroll
            for (int nt = 0; nt < 4; ++nt) {
                const int c0 = bn + wn + nt * 16 + kg * 4;
                f32x4 bv = *(const f32x4*)(bias + c0);
                f32x4 o;
#pragma unroll
                for (int r = 0; r < 4; ++r) o[r] = acc[mt][nt][r] + bv[r];
                *(f32x4*)(Cf + (size_t)row * N + c0) = o;
            }
        }
    } else {
        const int sec = bn >> 10;
        if (sec < 2) {
            // unswapped frags; per-lane col=ln15 fixed, rows vary -> scalar
            // u16 stores
            unsigned short* dst = sec == 0 ? q_out : k_out;
            const float scale = sec == 0 ? 0.125f : 1.0f;  // q pre-scale (pow2)
#pragma unroll
            for (int nt = 0; nt < 4; ++nt) {
                const int col = bn + wn + nt * 16 + ln15;
                const int h = (col >> 6) & 15, d = col & 63;
#pragma unroll
                for (int mt = 0; mt < 4; ++mt) {
#pragma unroll
                    for (int r = 0; r < 4; ++r) {
                        const int row = bm + wm + mt * 16 + kg * 4 + r;
                        const int b = row >> 11, t = row & 2047;
                        dst[((size_t)(b * 16 + h) * 2048 + t) * 64 + d] =
                            f2bf(acc[mt][nt][r] * scale);
                    }
                }
            }
        } else {
            // unswapped; pf_build over mt-pairs -> lane holds col d=ln15 fixed,
            // rows t contiguous -> writes vT[bh][d][t] directly (T=2048)
#pragma unroll
            for (int nt = 0; nt < 4; ++nt) {
                const int c = bn + wn + nt * 16 + ln15;
                const int h = (c >> 6) & 15, d = c & 63;
#pragma unroll
                for (int mp = 0; mp < 2; ++mp) {
                    const int t0 = bm + wm + mp * 32 + kg * 8;
                    const int b = t0 >> 11, t = t0 & 2047;
                    bf16x8 pf = pf_build_s(acc[2 * mp][nt], acc[2 * mp + 1][nt], 1.0f);
                    *(bf16x8*)(v_out + ((size_t)(b * 16 + h) * 64 + d) * 2048 + t) = pf;
                }
            }
        }
    }
}

// mask (diagonal block) + exp + in-register transpose + row-sum accumulate
__device__ __forceinline__ void softmax_tile(
    f32x4 sr[4], bool diag, int q_loc, int kg,
    bf16x8& pf0, bf16x8& pf1, f32x4& accl, bf16x8 ones)
{
    if (diag) {
#pragma unroll
        for (int kt = 0; kt < 4; ++kt)
#pragma unroll
            for (int r = 0; r < 4; ++r)
                if (kt * 16 + kg * 4 + r > q_loc) sr[kt][r] = -1e30f;
    }
    f32x4 pe[4];
#pragma unroll
    for (int kt = 0; kt < 4; ++kt)
#pragma unroll
        for (int r = 0; r < 4; ++r) pe[kt][r] = __expf(sr[kt][r]);
    pf0 = pf_build_s(pe[0], pe[1], 1.0f);
    pf1 = pf_build_s(pe[2], pe[3], 1.0f);
    accl = __builtin_amdgcn_mfma_f32_16x16x32_bf16(pf0, ones, accl, 0, 0, 0);
    accl = __builtin_amdgcn_mfma_f32_16x16x32_bf16(pf1, ones, accl, 0, 0, 0);
}

// ---------------------------------------------------------------------------
// MFMA flash attention v7 (causal). Q pre-scaled by 1/8. Q/K in [BH,T,64],
// V pre-transposed [BH,64,T]; O -> [B,T,H*64] bf16.
//
// v6 post-mortem: 43 us = 33 iters x ~3100 cyc -- the whole grid (512 blocks,
// 2/CU balanced) finishes in ONE block's serial critical path, and ~2/3 of
// each iteration was stall: per-iter __syncthreads + LDS staging forced every
// wave to wait on the slowest wave's global loads with only 2 waves/SIMD to
// hide it.
//
// v7: NO LDS AT ALL (guide lesson m169: don't stage what L2-fits -- K+V per
// head = 512 KB, ~4 heads/XCD = 2 MB < 4 MB L2; the block's 4 waves touch the
// same 16 KB tile near-simultaneously -> L1 hits). K/V fragments are read
// straight from global with the same 16B-contiguous per-lane addresses the
// LDS reads used. Zero barriers: waves fully independent, compiler free to
// hoist next-iteration loads across softmax/PV. s_setprio(1) around MFMA
// clusters (T5: +4-7% on independent-wave attn, m191).
//
// Balanced strip pairing kept: block x owns strips x and 31-x = 33 iters.
// Swapped QK^T + in-register P transpose (cvt_pk + permlane) kept.
// ---------------------------------------------------------------------------
__global__ __launch_bounds__(256) void flash_attn(
    const unsigned short* __restrict__ Q,
    const unsigned short* __restrict__ Km,
    const unsigned short* __restrict__ Vtg,
    unsigned short* __restrict__ O,
    int T, int H)
{
    const int tid  = threadIdx.x;
    const int wave = tid >> 6;
    const int lane = tid & 63;
    const int ln15 = lane & 15;
    const int kg   = lane >> 4;
    const int sA   = blockIdx.x;              // 0..15
    const int sB   = (T >> 6) - 1 - sA;       // 31..16
    const int kmax = sB;
    const int bh   = blockIdx.y;
    const int b    = bh >> 4, h = bh & 15;
    const size_t base  = (size_t)bh * T * 64;
    const size_t vbase = (size_t)bh * 64 * T;
    const int q_loc = wave * 16 + ln15;       // query row within strip

    bf16x8 qf[2][2];
    {
        const unsigned short* QrA = Q + base + (size_t)(sA * 64 + q_loc) * 64;
        const unsigned short* QrB = Q + base + (size_t)(sB * 64 + q_loc) * 64;
        qf[0][0] = *(const bf16x8*)(QrA + kg * 8);
        qf[0][1] = *(const bf16x8*)(QrA + 32 + kg * 8);
        qf[1][0] = *(const bf16x8*)(QrB + kg * 8);
        qf[1][1] = *(const bf16x8*)(QrB + 32 + kg * 8);
    }

    bf16x8 ones;
    {
        const short o = (ln15 == 0) ? (short)0x3F80 : (short)0;
#pragma unroll
        for (int j = 0; j < 8; ++j) ones[j] = o;
    }

    f32x4 o_acc[2][4];
#pragma unroll
    for (int s = 0; s < 2; ++s)
#pragma unroll
        for (int dt = 0; dt < 4; ++dt) o_acc[s][dt] = (f32x4){0.f, 0.f, 0.f, 0.f};
    f32x4 acc_l[2] = {(f32x4){0.f, 0.f, 0.f, 0.f}, (f32x4){0.f, 0.f, 0.f, 0.f}};

    // per-lane K/V fragment base pointers (16B-contiguous per lane):
    //   kf0(kt) = Km[base + (k0+kt*16+ln15)*64 + kg*8],     kf1 = +32
    //   vf0(dt) = Vtg[vbase + (dt*16+ln15)*T + k0 + kg*8],  vf1 = +32
    const unsigned short* Kl = Km + base + (size_t)ln15 * 64 + kg * 8;
    const unsigned short* Vl = Vtg + vbase + (size_t)ln15 * T + kg * 8;

    for (int kb = 0; kb <= kmax; ++kb) {
        const int k0 = kb * 64;
        const bool doA = (kb <= sA);

        f32x4 srB[4], srA[4];
        __builtin_amdgcn_s_setprio(1);
#pragma unroll
        for (int kt = 0; kt < 4; ++kt) {
            const unsigned short* kp = Kl + (size_t)(k0 + kt * 16) * 64;
            bf16x8 kf0 = *(const bf16x8*)(kp);
            bf16x8 kf1 = *(const bf16x8*)(kp + 32);
            f32x4 a = (f32x4){0.f, 0.f, 0.f, 0.f};
            a = __builtin_amdgcn_mfma_f32_16x16x32_bf16(kf0, qf[1][0], a, 0, 0, 0);
            a = __builtin_amdgcn_mfma_f32_16x16x32_bf16(kf1, qf[1][1], a, 0, 0, 0);
            srB[kt] = a;
            if (doA) {
                f32x4 c = (f32x4){0.f, 0.f, 0.f, 0.f};
                c = __builtin_amdgcn_mfma_f32_16x16x32_bf16(kf0, qf[0][0], c, 0, 0, 0);
                c = __builtin_amdgcn_mfma_f32_16x16x32_bf16(kf1, qf[0][1], c, 0, 0, 0);
                srA[kt] = c;
            }
        }
        __builtin_amdgcn_s_setprio(0);

        bf16x8 pfB0, pfB1, pfA0, pfA1;
        softmax_tile(srB, kb == sB, q_loc, kg, pfB0, pfB1, acc_l[1], ones);
        if (doA)
            softmax_tile(srA, kb == sA, q_loc, kg, pfA0, pfA1, acc_l[0], ones);

        __builtin_amdgcn_s_setprio(1);
#pragma unroll
        for (int dt = 0; dt < 4; ++dt) {
            const unsigned short* vp = Vl + (size_t)(dt * 16) * T + k0;
            bf16x8 vf0 = *(const bf16x8*)(vp);
            bf16x8 vf1 = *(const bf16x8*)(vp + 32);
            o_acc[1][dt] = __builtin_amdgcn_mfma_f32_16x16x32_bf16(pfB0, vf0, o_acc[1][dt], 0, 0, 0);
            o_acc[1][dt] = __builtin_amdgcn_mfma_f32_16x16x32_bf16(pfB1, vf1, o_acc[1][dt], 0, 0, 0);
            if (doA) {
                o_acc[0][dt] = __builtin_amdgcn_mfma_f32_16x16x32_bf16(pfA0, vf0, o_acc[0][dt], 0, 0, 0);
                o_acc[0][dt] = __builtin_amdgcn_mfma_f32_16x16x32_bf16(pfA1, vf1, o_acc[0][dt], 0, 0, 0);
            }
        }
        __builtin_amdgcn_s_setprio(0);
    }

    // normalize; l for row kg*4+r sits in lane kg*16 (col 0)
#pragma unroll
    for (int s = 0; s < 2; ++s) {
        const int qb = (s == 0 ? sA : sB) * 64;
        float inv[4];
#pragma unroll
        for (int r = 0; r < 4; ++r)
            inv[r] = 1.0f / __shfl(acc_l[s][r], lane & 48, 64);
#pragma unroll
        for (int dt = 0; dt < 4; ++dt)
#pragma unroll
            for (int r = 0; r < 4; ++r) {
                const int t = qb + wave * 16 + kg * 4 + r;
                const int d = dt * 16 + ln15;
                O[(size_t)(b * T + t) * (H * 64) + h * 64 + d] =
                    f2bf(o_acc[s][dt][r] * inv[r]);
            }
    }
}

extern "C" void kernel_launch(void* const* d_in, const int* in_sizes, int n_in,
                              void* d_out, int out_size, void* d_ws, size_t ws_size,
                              hipStream_t stream)
{
    const int B = 2, T = 2048, E = 1024, H = 16;
    const int M = B * T;  // 4096

    const float* x  = (const float*)d_in[0];
    const float* Wq = (const float*)d_in[1];
    const float* Wk = (const float*)d_in[2];
    const float* Wv = (const float*)d_in[3];
    const float* Wo = (const float*)d_in[4];
    const float* bo = (const float*)d_in[5];
    float* out = (float*)d_out;

    // workspace (bf16): xb 8MB, WqkvT 6MB, WoT 2MB, q/k/vT 8MB x3, ao 8MB
    unsigned short* xb     = (unsigned short*)d_ws;
    unsigned short* WqkvT  = xb + (size_t)M * E;            // [3072][1024]
    unsigned short* WoT    = WqkvT + (size_t)3 * E * E;     // [1024][1024]
    unsigned short* q      = WoT + (size_t)E * E;           // [BH][T][64]
    unsigned short* k      = q + (size_t)M * E;
    unsigned short* vT     = k + (size_t)M * E;             // [BH][64][T]
    unsigned short* ao     = vT + (size_t)M * E;            // [M][E]

    // fused convert + 4x weight transpose (1 launch)
    prep<<<8192, 256, 0, stream>>>(x, Wq, Wk, Wv, Wo, xb, WqkvT, WoT);

    // fused QKV projection: [4096,1024] @ [1024,3072]; V written transposed
    dim3 g1(M / 128, 3 * E / 128);
    gemm128<1><<<g1, 256, 0, stream>>>(xb, WqkvT, nullptr, nullptr, q, k, vT,
                                       M, 3 * E, E);

    // flash attention: 16 balanced strip-pair blocks x 32 bh, barrier-free
    dim3 ag(T / 128, B * H);
    flash_attn<<<ag, 256, 0, stream>>>(q, k, vT, ao, T, H);

    dim3 g2(M / 128, E / 128);
    gemm128<0><<<g2, 256, 0, stream>>>(ao, WoT, bo, out, nullptr, nullptr, nullptr,
                                       M, E, E);
}

// Round 5
// 198.908 us; speedup vs baseline: 1.3286x; 1.3286x over previous
//
#include <hip/hip_runtime.h>
#include <hip/hip_bf16.h>

typedef __attribute__((ext_vector_type(8))) short bf16x8;
typedef __attribute__((ext_vector_type(4))) float f32x4;
typedef __attribute__((ext_vector_type(4))) unsigned short u16x4;

__device__ __forceinline__ unsigned short f2bf(float f) {
    union { float f; unsigned int i; } x; x.f = f;
    unsigned int lsb = (x.i >> 16) & 1u;
    x.i += 0x7fffu + lsb;  // round-to-nearest-even
    return (unsigned short)(x.i >> 16);
}

// async global->LDS DMA, 16B per lane; lds ptr wave-uniform, HW adds lane*16
__device__ __forceinline__ void gl_lds16(const unsigned short* g, unsigned short* l) {
    __builtin_amdgcn_global_load_lds(
        (const __attribute__((address_space(1))) void*)g,
        (__attribute__((address_space(3))) void*)l, 16, 0, 0);
}

__device__ __forceinline__ unsigned int cvt_pk_bf16(float lo, float hi) {
    unsigned int d;
    asm("v_cvt_pk_bf16_f32 %0, %1, %2" : "=v"(d) : "v"(lo), "v"(hi));
    return d;
}

// In-register 16x32 C-fragment transpose -> A-frag/store layout (attn-verified).
// Input: pa = C-frag rows 0..15 of a 32-row span (per-lane row=kg*4+r, col=ln15),
//        pb = rows 16..31. Output: lane (kg,ln15) holds bf16 of rows kg*8..kg*8+7
// at fixed col=ln15 -> one contiguous 16B run along the row direction.
__device__ __forceinline__ bf16x8 pf_build_s(f32x4 pa, f32x4 pb, float s) {
    unsigned int E0 = cvt_pk_bf16(pa[0] * s, pa[1] * s);
    unsigned int O0 = cvt_pk_bf16(pa[2] * s, pa[3] * s);
    unsigned int E1 = cvt_pk_bf16(pb[0] * s, pb[1] * s);
    unsigned int O1 = cvt_pk_bf16(pb[2] * s, pb[3] * s);
    asm("v_permlane32_swap_b32 %0, %1" : "+v"(E0), "+v"(E1));
    asm("v_permlane32_swap_b32 %0, %1" : "+v"(O0), "+v"(O1));
    asm("v_permlane16_swap_b32 %0, %1" : "+v"(E0), "+v"(E1));
    asm("v_permlane16_swap_b32 %0, %1" : "+v"(O0), "+v"(O1));
    union { unsigned int u[4]; bf16x8 v; } r;
    r.u[0] = E0; r.u[1] = O0; r.u[2] = E1; r.u[3] = O1;
    return r.v;
}

// ---------------------------------------------------------------------------
// fused preprocessing: blocks [0,4096) = fp32->bf16 convert of x (x4 vec);
// blocks [4096,8192) = 32x32 transpose+convert of the 4 weight matrices.
// ---------------------------------------------------------------------------
__global__ __launch_bounds__(256) void prep(
    const float* __restrict__ x,
    const float* __restrict__ Wq, const float* __restrict__ Wk,
    const float* __restrict__ Wv, const float* __restrict__ Wo,
    unsigned short* __restrict__ xb,
    unsigned short* __restrict__ WqkvT, unsigned short* __restrict__ WoT)
{
    const int E = 1024;
    const int bid = blockIdx.x;
    __shared__ float t[32][33];

    if (bid < 4096) {                       // x convert: 4096*256*4 = 4M elems
        int i = bid * 256 + threadIdx.x;
        f32x4 v = ((const f32x4*)x)[i];
        u16x4 o;
#pragma unroll
        for (int j = 0; j < 4; ++j) o[j] = f2bf(v[j]);
        ((u16x4*)xb)[i] = o;
        return;
    }
    const int r = bid - 4096;
    const int which = r >> 10;              // 0..3 : Wq,Wk,Wv,Wo
    const int sub = r & 1023;
    const float* src = which == 0 ? Wq : which == 1 ? Wk : which == 2 ? Wv : Wo;
    unsigned short* dst = which == 3 ? WoT : WqkvT + (size_t)which * E * E;

    const int tx = threadIdx.x & 31, ty = threadIdx.x >> 5;  // ty 0..7
    const int n0 = (sub & 31) * 32, k0 = (sub >> 5) * 32;
#pragma unroll
    for (int i = 0; i < 4; ++i)
        t[ty + 8 * i][tx] = src[(size_t)(k0 + ty + 8 * i) * E + n0 + tx];
    __syncthreads();
#pragma unroll
    for (int i = 0; i < 4; ++i)
        dst[(size_t)(n0 + ty + 8 * i) * E + k0 + tx] = f2bf(t[tx][ty + 8 * i]);
}

// ---------------------------------------------------------------------------
// m97-style GEMM: C = A[M,K] @ BT[N,K]^T, bf16 in, fp32 acc. 128x128 tile,
// BK=32, 256 thr = 4 waves 2x2; 16 MFMA + 8 ds_read_b128 per K-step/wave;
// staging via global_load_lds dwordx4.
//
// SINGLE-PATH main loop per template instantiation (round-2 lesson: a
// uniform-but-runtime swap branch around the MFMAs inside the K-loop cost
// 48% -- MfmaUtil 21.6->14.9, VGPR 72->92. PERM is compile-time, so each
// instantiation has exactly one MFMA ordering and no loop-body branches).
//
// PERM=1 (QKV): unswapped mfma(af,bw). Epilogue: q/k scalar u16 stores; the
// v section uses the in-register fragment transpose (pf_build) whose
// t-contiguous output writes V TRANSPOSED [bh][d][t] directly.
// PERM=0 (out-proj): swapped mfma(bw,af) = C^T frags (compile-time path),
// epilogue = f32x4 bias+store, fully vectorized.
// ---------------------------------------------------------------------------
template <int PERM>
__global__ __launch_bounds__(256) void gemm128(
    const unsigned short* __restrict__ A,
    const unsigned short* __restrict__ BT,
    const float* __restrict__ bias,
    float* __restrict__ Cf,
    unsigned short* __restrict__ q_out,
    unsigned short* __restrict__ k_out,
    unsigned short* __restrict__ v_out,   // [bh][64][T] transposed
    int M, int N, int K)
{
    __shared__ __align__(16) unsigned short As[128 * 32];
    __shared__ __align__(16) unsigned short Bs[128 * 32];

    const int tid  = threadIdx.x;
    const int wave = tid >> 6;
    const int lane = tid & 63;
    const int ln15 = lane & 15;
    const int kg   = lane >> 4;
    const int bm = blockIdx.x * 128, bn = blockIdx.y * 128;
    const int wm = (wave >> 1) * 64, wn = (wave & 1) * 64;

    f32x4 acc[4][4];
#pragma unroll
    for (int i = 0; i < 4; ++i)
#pragma unroll
        for (int j = 0; j < 4; ++j) acc[i][j] = (f32x4){0.f, 0.f, 0.f, 0.f};

    const int sr = wave * 32 + (lane >> 2);
    const int sc = (lane & 3) * 8;

    for (int k0 = 0; k0 < K; k0 += 32) {
        gl_lds16(A  + (size_t)(bm + sr)      * K + k0 + sc, As + wave * 1024);
        gl_lds16(A  + (size_t)(bm + sr + 16) * K + k0 + sc, As + wave * 1024 + 512);
        gl_lds16(BT + (size_t)(bn + sr)      * K + k0 + sc, Bs + wave * 1024);
        gl_lds16(BT + (size_t)(bn + sr + 16) * K + k0 + sc, Bs + wave * 1024 + 512);
        __syncthreads();

        bf16x8 af[4], bw[4];
#pragma unroll
        for (int mt = 0; mt < 4; ++mt)
            af[mt] = *(const bf16x8*)&As[(wm + mt * 16 + ln15) * 32 + kg * 8];
#pragma unroll
        for (int nt = 0; nt < 4; ++nt)
            bw[nt] = *(const bf16x8*)&Bs[(wn + nt * 16 + ln15) * 32 + kg * 8];
        if (PERM == 0) {   // compile-time: C^T fragments
#pragma unroll
            for (int mt = 0; mt < 4; ++mt)
#pragma unroll
                for (int nt = 0; nt < 4; ++nt)
                    acc[mt][nt] = __builtin_amdgcn_mfma_f32_16x16x32_bf16(
                        bw[nt], af[mt], acc[mt][nt], 0, 0, 0);
        } else {           // compile-time: C fragments
#pragma unroll
            for (int mt = 0; mt < 4; ++mt)
#pragma unroll
                for (int nt = 0; nt < 4; ++nt)
                    acc[mt][nt] = __builtin_amdgcn_mfma_f32_16x16x32_bf16(
                        af[mt], bw[nt], acc[mt][nt], 0, 0, 0);
        }
        __syncthreads();
    }

    if (PERM == 0) {
        // swapped: acc[mt][nt][r] = C[row=bm+wm+mt*16+ln15][col=bn+wn+nt*16+kg*4+r]
#pragma unroll
        for (int mt = 0; mt < 4; ++mt) {
            const int row = bm + wm + mt * 16 + ln15;
#pragma unroll
            for (int nt = 0; nt < 4; ++nt) {
                const int c0 = bn + wn + nt * 16 + kg * 4;
                f32x4 bv = *(const f32x4*)(bias + c0);
                f32x4 o;
#pragma unroll
                for (int r = 0; r < 4; ++r) o[r] = acc[mt][nt][r] + bv[r];
                *(f32x4*)(Cf + (size_t)row * N + c0) = o;
            }
        }
    } else {
        const int sec = bn >> 10;
        if (sec < 2) {
            // unswapped frags; per-lane col=ln15 fixed, rows vary -> scalar
            // u16 stores
            unsigned short* dst = sec == 0 ? q_out : k_out;
            const float scale = sec == 0 ? 0.125f : 1.0f;  // q pre-scale (pow2)
#pragma unroll
            for (int nt = 0; nt < 4; ++nt) {
                const int col = bn + wn + nt * 16 + ln15;
                const int h = (col >> 6) & 15, d = col & 63;
#pragma unroll
                for (int mt = 0; mt < 4; ++mt) {
#pragma unroll
                    for (int r = 0; r < 4; ++r) {
                        const int row = bm + wm + mt * 16 + kg * 4 + r;
                        const int b = row >> 11, t = row & 2047;
                        dst[((size_t)(b * 16 + h) * 2048 + t) * 64 + d] =
                            f2bf(acc[mt][nt][r] * scale);
                    }
                }
            }
        } else {
            // unswapped; pf_build over mt-pairs -> lane holds col d=ln15 fixed,
            // rows t contiguous -> writes vT[bh][d][t] directly (T=2048)
#pragma unroll
            for (int nt = 0; nt < 4; ++nt) {
                const int c = bn + wn + nt * 16 + ln15;
                const int h = (c >> 6) & 15, d = c & 63;
#pragma unroll
                for (int mp = 0; mp < 2; ++mp) {
                    const int t0 = bm + wm + mp * 32 + kg * 8;
                    const int b = t0 >> 11, t = t0 & 2047;
                    bf16x8 pf = pf_build_s(acc[2 * mp][nt], acc[2 * mp + 1][nt], 1.0f);
                    *(bf16x8*)(v_out + ((size_t)(b * 16 + h) * 64 + d) * 2048 + t) = pf;
                }
            }
        }
    }
}

// mask (diagonal block) + exp + in-register transpose + row-sum accumulate
__device__ __forceinline__ void softmax_tile(
    f32x4 sr[4], bool diag, int q_loc, int kg,
    bf16x8& pf0, bf16x8& pf1, f32x4& accl, bf16x8 ones)
{
    if (diag) {
#pragma unroll
        for (int kt = 0; kt < 4; ++kt)
#pragma unroll
            for (int r = 0; r < 4; ++r)
                if (kt * 16 + kg * 4 + r > q_loc) sr[kt][r] = -1e30f;
    }
    f32x4 pe[4];
#pragma unroll
    for (int kt = 0; kt < 4; ++kt)
#pragma unroll
        for (int r = 0; r < 4; ++r) pe[kt][r] = __expf(sr[kt][r]);
    pf0 = pf_build_s(pe[0], pe[1], 1.0f);
    pf1 = pf_build_s(pe[2], pe[3], 1.0f);
    accl = __builtin_amdgcn_mfma_f32_16x16x32_bf16(pf0, ones, accl, 0, 0, 0);
    accl = __builtin_amdgcn_mfma_f32_16x16x32_bf16(pf1, ones, accl, 0, 0, 0);
}

// ---------------------------------------------------------------------------
// MFMA flash attention v8 (causal). Q pre-scaled by 1/8. Q/K in [BH,T,64],
// V pre-transposed [BH,64,T]; O -> [B,T,H*64] bf16.
//
// v7 post-mortem (REVERTED): reading K/V straight from global was 3x slower
// (127 us, FETCH 62.5 MB at 569 GB/s) -- blocks sharing a head scatter across
// XCDs so L2 thrashed, and dropping LDS staging quadrupled per-wave loads
// while exposing raw load latency at 2 waves/SIMD. The v6 staged iteration
// (double-buffered LDS, ONE barrier/iter, register prefetch) is kept
// byte-level intact here.
//
// v8 change: PARALLELISM, not the iteration. v6's 512 paired blocks = only
// 2 blocks/CU to overlap barrier/staging stalls (latency-bound at ~43 us).
// Un-pair: one 64-query strip per block -> grid (32 strips, 32 bh) = 1024
// blocks = 4/CU (LDS 36.8 KB caps at exactly 4). Same total work (66
// iters/CU), twice the co-resident blocks to hide each other's stalls.
// Load balance: strip s costs s+1 iters; heavy-first order (s = 31-bx) +
// greedy HW dispatch ~= LPT scheduling -> per-CU totals near the 66 ideal.
// ---------------------------------------------------------------------------
__global__ __launch_bounds__(256) void flash_attn(
    const unsigned short* __restrict__ Q,
    const unsigned short* __restrict__ Km,
    const unsigned short* __restrict__ Vtg,
    unsigned short* __restrict__ O,
    int T, int H)
{
    __shared__ __align__(16) unsigned short Ks[2][64][72];   // [buf][key][d]
    __shared__ __align__(16) unsigned short Vs[2][64][72];   // [buf][d][key]

    const int tid  = threadIdx.x;
    const int wave = tid >> 6;
    const int lane = tid & 63;
    const int ln15 = lane & 15;
    const int kg   = lane >> 4;
    const int s    = (T >> 6) - 1 - blockIdx.x;  // 31..0, heavy first
    const int kmax = s;
    const int bh   = blockIdx.y;
    const int b    = bh >> 4, h = bh & 15;
    const size_t base  = (size_t)bh * T * 64;
    const size_t vbase = (size_t)bh * 64 * T;
    const int q_loc = wave * 16 + ln15;          // query row within strip

    bf16x8 qf[2];
    {
        const unsigned short* Qr = Q + base + (size_t)(s * 64 + q_loc) * 64;
        qf[0] = *(const bf16x8*)(Qr + kg * 8);
        qf[1] = *(const bf16x8*)(Qr + 32 + kg * 8);
    }

    bf16x8 ones;
    {
        const short o = (ln15 == 0) ? (short)0x3F80 : (short)0;
#pragma unroll
        for (int j = 0; j < 8; ++j) ones[j] = o;
    }

    f32x4 o_acc[4];
#pragma unroll
    for (int dt = 0; dt < 4; ++dt) o_acc[dt] = (f32x4){0.f, 0.f, 0.f, 0.f};
    f32x4 acc_l = (f32x4){0.f, 0.f, 0.f, 0.f};

    const int sky = tid >> 3;             // 0..31
    const int sd  = (tid & 7) * 8;

    // prefetch key-block 0 into registers
    bf16x8 pk0, pk1, pv0, pv1;
    pk0 = *(const bf16x8*)(Km + base + (size_t)sky * 64 + sd);
    pk1 = *(const bf16x8*)(Km + base + (size_t)(sky + 32) * 64 + sd);
    pv0 = *(const bf16x8*)(Vtg + vbase + (size_t)sky * T + sd);
    pv1 = *(const bf16x8*)(Vtg + vbase + (size_t)(sky + 32) * T + sd);

    for (int kb = 0; kb <= kmax; ++kb) {
        const int bufi = kb & 1;
        // stage current block (buffer kb&1; last read 2 barriers ago -> safe)
        *(bf16x8*)&Ks[bufi][sky][sd]      = pk0;
        *(bf16x8*)&Ks[bufi][sky + 32][sd] = pk1;
        *(bf16x8*)&Vs[bufi][sky][sd]      = pv0;
        *(bf16x8*)&Vs[bufi][sky + 32][sd] = pv1;
        if (kb < kmax) {  // issue next block's loads; latency hides under compute
            const int kn = (kb + 1) * 64;
            pk0 = *(const bf16x8*)(Km + base + (size_t)(kn + sky) * 64 + sd);
            pk1 = *(const bf16x8*)(Km + base + (size_t)(kn + sky + 32) * 64 + sd);
            pv0 = *(const bf16x8*)(Vtg + vbase + (size_t)sky * T + kn + sd);
            pv1 = *(const bf16x8*)(Vtg + vbase + (size_t)(sky + 32) * T + kn + sd);
        }
        __syncthreads();   // staging of buf visible; buf^1 free next iter

        // S^T-layout scores: mfma(K,Q) -> lane holds S[q=ln15][key=kt*16+kg*4+r]
        f32x4 sr[4];
#pragma unroll
        for (int kt = 0; kt < 4; ++kt) {
            bf16x8 kf0 = *(const bf16x8*)&Ks[bufi][kt * 16 + ln15][kg * 8];
            bf16x8 kf1 = *(const bf16x8*)&Ks[bufi][kt * 16 + ln15][32 + kg * 8];
            f32x4 a = (f32x4){0.f, 0.f, 0.f, 0.f};
            a = __builtin_amdgcn_mfma_f32_16x16x32_bf16(kf0, qf[0], a, 0, 0, 0);
            a = __builtin_amdgcn_mfma_f32_16x16x32_bf16(kf1, qf[1], a, 0, 0, 0);
            sr[kt] = a;
        }

        bf16x8 pf0, pf1;
        softmax_tile(sr, kb == kmax, q_loc, kg, pf0, pf1, acc_l, ones);

        // O += P V ; V frags from LDS
#pragma unroll
        for (int dt = 0; dt < 4; ++dt) {
            bf16x8 vf0 = *(const bf16x8*)&Vs[bufi][dt * 16 + ln15][kg * 8];
            bf16x8 vf1 = *(const bf16x8*)&Vs[bufi][dt * 16 + ln15][32 + kg * 8];
            o_acc[dt] = __builtin_amdgcn_mfma_f32_16x16x32_bf16(pf0, vf0, o_acc[dt], 0, 0, 0);
            o_acc[dt] = __builtin_amdgcn_mfma_f32_16x16x32_bf16(pf1, vf1, o_acc[dt], 0, 0, 0);
        }
    }

    // normalize; l for row kg*4+r sits in lane kg*16 (col 0)
    float inv[4];
#pragma unroll
    for (int r = 0; r < 4; ++r)
        inv[r] = 1.0f / __shfl(acc_l[r], lane & 48, 64);
#pragma unroll
    for (int dt = 0; dt < 4; ++dt)
#pragma unroll
        for (int r = 0; r < 4; ++r) {
            const int t = s * 64 + wave * 16 + kg * 4 + r;
            const int d = dt * 16 + ln15;
            O[(size_t)(b * T + t) * (H * 64) + h * 64 + d] =
                f2bf(o_acc[dt][r] * inv[r]);
        }
}

extern "C" void kernel_launch(void* const* d_in, const int* in_sizes, int n_in,
                              void* d_out, int out_size, void* d_ws, size_t ws_size,
                              hipStream_t stream)
{
    const int B = 2, T = 2048, E = 1024, H = 16;
    const int M = B * T;  // 4096

    const float* x  = (const float*)d_in[0];
    const float* Wq = (const float*)d_in[1];
    const float* Wk = (const float*)d_in[2];
    const float* Wv = (const float*)d_in[3];
    const float* Wo = (const float*)d_in[4];
    const float* bo = (const float*)d_in[5];
    float* out = (float*)d_out;

    // workspace (bf16): xb 8MB, WqkvT 6MB, WoT 2MB, q/k/vT 8MB x3, ao 8MB
    unsigned short* xb     = (unsigned short*)d_ws;
    unsigned short* WqkvT  = xb + (size_t)M * E;            // [3072][1024]
    unsigned short* WoT    = WqkvT + (size_t)3 * E * E;     // [1024][1024]
    unsigned short* q      = WoT + (size_t)E * E;           // [BH][T][64]
    unsigned short* k      = q + (size_t)M * E;
    unsigned short* vT     = k + (size_t)M * E;             // [BH][64][T]
    unsigned short* ao     = vT + (size_t)M * E;            // [M][E]

    // fused convert + 4x weight transpose (1 launch)
    prep<<<8192, 256, 0, stream>>>(x, Wq, Wk, Wv, Wo, xb, WqkvT, WoT);

    // fused QKV projection: [4096,1024] @ [1024,3072]; V written transposed
    dim3 g1(M / 128, 3 * E / 128);
    gemm128<1><<<g1, 256, 0, stream>>>(xb, WqkvT, nullptr, nullptr, q, k, vT,
                                       M, 3 * E, E);

    // flash attention: 32 single-strip blocks (heavy first) x 32 bh = 4/CU
    dim3 ag(T / 64, B * H);
    flash_attn<<<ag, 256, 0, stream>>>(q, k, vT, ao, T, H);

    dim3 g2(M / 128, E / 128);
    gemm128<0><<<g2, 256, 0, stream>>>(ao, WoT, bo, out, nullptr, nullptr, nullptr,
                                       M, E, E);
}

// Round 7
// 182.855 us; speedup vs baseline: 1.4452x; 1.0878x over previous
//
#include <hip/hip_runtime.h>
#include <hip/hip_bf16.h>

typedef __attribute__((ext_vector_type(8))) short bf16x8;
typedef __attribute__((ext_vector_type(4))) float f32x4;
typedef __attribute__((ext_vector_type(4))) unsigned short u16x4;

__device__ __forceinline__ unsigned short f2bf(float f) {
    union { float f; unsigned int i; } x; x.f = f;
    unsigned int lsb = (x.i >> 16) & 1u;
    x.i += 0x7fffu + lsb;  // round-to-nearest-even
    return (unsigned short)(x.i >> 16);
}

// async global->LDS DMA, 16B per lane; lds ptr wave-uniform, HW adds lane*16
__device__ __forceinline__ void gl_lds16(const unsigned short* g, unsigned short* l) {
    __builtin_amdgcn_global_load_lds(
        (const __attribute__((address_space(1))) void*)g,
        (__attribute__((address_space(3))) void*)l, 16, 0, 0);
}

__device__ __forceinline__ unsigned int cvt_pk_bf16(float lo, float hi) {
    unsigned int d;
    asm("v_cvt_pk_bf16_f32 %0, %1, %2" : "=v"(d) : "v"(lo), "v"(hi));
    return d;
}

// In-register 16x32 C-fragment transpose -> A-frag/store layout (attn-verified).
// Input: pa = C-frag rows 0..15 of a 32-row span (per-lane row=kg*4+r, col=ln15),
//        pb = rows 16..31. Output: lane (kg,ln15) holds bf16 of rows kg*8..kg*8+7
// at fixed col=ln15 -> one contiguous 16B run along the row direction.
__device__ __forceinline__ bf16x8 pf_build_s(f32x4 pa, f32x4 pb, float s) {
    unsigned int E0 = cvt_pk_bf16(pa[0] * s, pa[1] * s);
    unsigned int O0 = cvt_pk_bf16(pa[2] * s, pa[3] * s);
    unsigned int E1 = cvt_pk_bf16(pb[0] * s, pb[1] * s);
    unsigned int O1 = cvt_pk_bf16(pb[2] * s, pb[3] * s);
    asm("v_permlane32_swap_b32 %0, %1" : "+v"(E0), "+v"(E1));
    asm("v_permlane32_swap_b32 %0, %1" : "+v"(O0), "+v"(O1));
    asm("v_permlane16_swap_b32 %0, %1" : "+v"(E0), "+v"(E1));
    asm("v_permlane16_swap_b32 %0, %1" : "+v"(O0), "+v"(O1));
    union { unsigned int u[4]; bf16x8 v; } r;
    r.u[0] = E0; r.u[1] = O0; r.u[2] = E1; r.u[3] = O1;
    return r.v;
}

// ---------------------------------------------------------------------------
// fused preprocessing: blocks [0,4096) = fp32->bf16 convert of x (x4 vec);
// blocks [4096,8192) = 32x32 transpose+convert of the 4 weight matrices.
// ---------------------------------------------------------------------------
__global__ __launch_bounds__(256) void prep(
    const float* __restrict__ x,
    const float* __restrict__ Wq, const float* __restrict__ Wk,
    const float* __restrict__ Wv, const float* __restrict__ Wo,
    unsigned short* __restrict__ xb,
    unsigned short* __restrict__ WqkvT, unsigned short* __restrict__ WoT)
{
    const int E = 1024;
    const int bid = blockIdx.x;
    __shared__ float t[32][33];

    if (bid < 4096) {                       // x convert: 4096*256*4 = 4M elems
        int i = bid * 256 + threadIdx.x;
        f32x4 v = ((const f32x4*)x)[i];
        u16x4 o;
#pragma unroll
        for (int j = 0; j < 4; ++j) o[j] = f2bf(v[j]);
        ((u16x4*)xb)[i] = o;
        return;
    }
    const int r = bid - 4096;
    const int which = r >> 10;              // 0..3 : Wq,Wk,Wv,Wo
    const int sub = r & 1023;
    const float* src = which == 0 ? Wq : which == 1 ? Wk : which == 2 ? Wv : Wo;
    unsigned short* dst = which == 3 ? WoT : WqkvT + (size_t)which * E * E;

    const int tx = threadIdx.x & 31, ty = threadIdx.x >> 5;  // ty 0..7
    const int n0 = (sub & 31) * 32, k0 = (sub >> 5) * 32;
#pragma unroll
    for (int i = 0; i < 4; ++i)
        t[ty + 8 * i][tx] = src[(size_t)(k0 + ty + 8 * i) * E + n0 + tx];
    __syncthreads();
#pragma unroll
    for (int i = 0; i < 4; ++i)
        dst[(size_t)(n0 + ty + 8 * i) * E + k0 + tx] = f2bf(t[tx][ty + 8 * i]);
}

// ---------------------------------------------------------------------------
// m97-style GEMM: C = A[M,K] @ BT[N,K]^T, bf16 in, fp32 acc. 128x128 tile,
// BK=32, 256 thr = 4 waves 2x2; 16 MFMA + 8 ds_read_b128 per K-step/wave;
// staging via global_load_lds dwordx4.
//
// SINGLE-PATH main loop per template instantiation (round-2 lesson: a
// uniform-but-runtime swap branch around the MFMAs inside the K-loop cost
// 48% -- MfmaUtil 21.6->14.9, VGPR 72->92. PERM is compile-time, so each
// instantiation has exactly one MFMA ordering and no loop-body branches).
//
// PERM=1 (QKV): unswapped mfma(af,bw). Epilogue: q/k scalar u16 stores; the
// v section uses the in-register fragment transpose (pf_build) whose
// t-contiguous output writes V TRANSPOSED [bh][d][t] directly.
// PERM=0 (out-proj): swapped mfma(bw,af) = C^T frags (compile-time path),
// epilogue = f32x4 bias+store, fully vectorized.
// ---------------------------------------------------------------------------
template <int PERM>
__global__ __launch_bounds__(256) void gemm128(
    const unsigned short* __restrict__ A,
    const unsigned short* __restrict__ BT,
    const float* __restrict__ bias,
    float* __restrict__ Cf,
    unsigned short* __restrict__ q_out,
    unsigned short* __restrict__ k_out,
    unsigned short* __restrict__ v_out,   // [bh][64][T] transposed
    int M, int N, int K)
{
    __shared__ __align__(16) unsigned short As[128 * 32];
    __shared__ __align__(16) unsigned short Bs[128 * 32];

    const int tid  = threadIdx.x;
    const int wave = tid >> 6;
    const int lane = tid & 63;
    const int ln15 = lane & 15;
    const int kg   = lane >> 4;
    const int bm = blockIdx.x * 128, bn = blockIdx.y * 128;
    const int wm = (wave >> 1) * 64, wn = (wave & 1) * 64;

    f32x4 acc[4][4];
#pragma unroll
    for (int i = 0; i < 4; ++i)
#pragma unroll
        for (int j = 0; j < 4; ++j) acc[i][j] = (f32x4){0.f, 0.f, 0.f, 0.f};

    const int sr = wave * 32 + (lane >> 2);
    const int sc = (lane & 3) * 8;

    for (int k0 = 0; k0 < K; k0 += 32) {
        gl_lds16(A  + (size_t)(bm + sr)      * K + k0 + sc, As + wave * 1024);
        gl_lds16(A  + (size_t)(bm + sr + 16) * K + k0 + sc, As + wave * 1024 + 512);
        gl_lds16(BT + (size_t)(bn + sr)      * K + k0 + sc, Bs + wave * 1024);
        gl_lds16(BT + (size_t)(bn + sr + 16) * K + k0 + sc, Bs + wave * 1024 + 512);
        __syncthreads();

        bf16x8 af[4], bw[4];
#pragma unroll
        for (int mt = 0; mt < 4; ++mt)
            af[mt] = *(const bf16x8*)&As[(wm + mt * 16 + ln15) * 32 + kg * 8];
#pragma unroll
        for (int nt = 0; nt < 4; ++nt)
            bw[nt] = *(const bf16x8*)&Bs[(wn + nt * 16 + ln15) * 32 + kg * 8];
        if (PERM == 0) {   // compile-time: C^T fragments
#pragma unroll
            for (int mt = 0; mt < 4; ++mt)
#pragma unroll
                for (int nt = 0; nt < 4; ++nt)
                    acc[mt][nt] = __builtin_amdgcn_mfma_f32_16x16x32_bf16(
                        bw[nt], af[mt], acc[mt][nt], 0, 0, 0);
        } else {           // compile-time: C fragments
#pragma unroll
            for (int mt = 0; mt < 4; ++mt)
#pragma unroll
                for (int nt = 0; nt < 4; ++nt)
                    acc[mt][nt] = __builtin_amdgcn_mfma_f32_16x16x32_bf16(
                        af[mt], bw[nt], acc[mt][nt], 0, 0, 0);
        }
        __syncthreads();
    }

    if (PERM == 0) {
        // swapped: acc[mt][nt][r] = C[row=bm+wm+mt*16+ln15][col=bn+wn+nt*16+kg*4+r]
#pragma unroll
        for (int mt = 0; mt < 4; ++mt) {
            const int row = bm + wm + mt * 16 + ln15;
#pragma unroll
            for (int nt = 0; nt < 4; ++nt) {
                const int c0 = bn + wn + nt * 16 + kg * 4;
                f32x4 bv = *(const f32x4*)(bias + c0);
                f32x4 o;
#pragma unroll
                for (int r = 0; r < 4; ++r) o[r] = acc[mt][nt][r] + bv[r];
                *(f32x4*)(Cf + (size_t)row * N + c0) = o;
            }
        }
    } else {
        const int sec = bn >> 10;
        if (sec < 2) {
            // unswapped frags; per-lane col=ln15 fixed, rows vary -> scalar
            // u16 stores
            unsigned short* dst = sec == 0 ? q_out : k_out;
            const float scale = sec == 0 ? 0.125f : 1.0f;  // q pre-scale (pow2)
#pragma unroll
            for (int nt = 0; nt < 4; ++nt) {
                const int col = bn + wn + nt * 16 + ln15;
                const int h = (col >> 6) & 15, d = col & 63;
#pragma unroll
                for (int mt = 0; mt < 4; ++mt) {
#pragma unroll
                    for (int r = 0; r < 4; ++r) {
                        const int row = bm + wm + mt * 16 + kg * 4 + r;
                        const int b = row >> 11, t = row & 2047;
                        dst[((size_t)(b * 16 + h) * 2048 + t) * 64 + d] =
                            f2bf(acc[mt][nt][r] * scale);
                    }
                }
            }
        } else {
            // unswapped; pf_build over mt-pairs -> lane holds col d=ln15 fixed,
            // rows t contiguous -> writes vT[bh][d][t] directly (T=2048)
#pragma unroll
            for (int nt = 0; nt < 4; ++nt) {
                const int c = bn + wn + nt * 16 + ln15;
                const int h = (c >> 6) & 15, d = c & 63;
#pragma unroll
                for (int mp = 0; mp < 2; ++mp) {
                    const int t0 = bm + wm + mp * 32 + kg * 8;
                    const int b = t0 >> 11, t = t0 & 2047;
                    bf16x8 pf = pf_build_s(acc[2 * mp][nt], acc[2 * mp + 1][nt], 1.0f);
                    *(bf16x8*)(v_out + ((size_t)(b * 16 + h) * 64 + d) * 2048 + t) = pf;
                }
            }
        }
    }
}

// mask (diagonal block) + exp + in-register transpose + row-sum accumulate
__device__ __forceinline__ void softmax_tile(
    f32x4 sr[4], bool diag, int q_loc, int kg,
    bf16x8& pf0, bf16x8& pf1, f32x4& accl, bf16x8 ones)
{
    if (diag) {
#pragma unroll
        for (int kt = 0; kt < 4; ++kt)
#pragma unroll
            for (int r = 0; r < 4; ++r)
                if (kt * 16 + kg * 4 + r > q_loc) sr[kt][r] = -1e30f;
    }
    f32x4 pe[4];
#pragma unroll
    for (int kt = 0; kt < 4; ++kt)
#pragma unroll
        for (int r = 0; r < 4; ++r) pe[kt][r] = __expf(sr[kt][r]);
    pf0 = pf_build_s(pe[0], pe[1], 1.0f);
    pf1 = pf_build_s(pe[2], pe[3], 1.0f);
    accl = __builtin_amdgcn_mfma_f32_16x16x32_bf16(pf0, ones, accl, 0, 0, 0);
    accl = __builtin_amdgcn_mfma_f32_16x16x32_bf16(pf1, ones, accl, 0, 0, 0);
}

// ---------------------------------------------------------------------------
// MFMA flash attention v6+T5 (causal). Q pre-scaled by 1/8. Q/K in [BH,T,64],
// V pre-transposed [BH,64,T]; O -> [B,T,H*64] bf16.
//
// R4-R6 post-mortems: no-LDS (v7, 3x slower), un-paired strips (v8, +28%
// staging traffic), and 8-wave split (v9, correctness FAIL, undiagnosed)
// all lose to this structure. v6's paired iteration is restored EXACTLY
// (R3-verified): block x owns strips sA=x, sB=31-x (33 iters, balanced);
// K/V staged once per block and shared by both strips; double-buffered LDS;
// ONE barrier per key-block; register prefetch of the next block's K/V.
//
// Only change vs R3: T5 s_setprio(1)/(0) around the two MFMA clusters.
// With 2 independent blocks/CU at unrelated phases, an MFMA-entering wave
// gets issue priority over the co-resident block's staging/softmax waves
// (m191: +4-7% on attn; touches no memory op, no barrier -> null-safe).
// ---------------------------------------------------------------------------
__global__ __launch_bounds__(256) void flash_attn(
    const unsigned short* __restrict__ Q,
    const unsigned short* __restrict__ Km,
    const unsigned short* __restrict__ Vtg,
    unsigned short* __restrict__ O,
    int T, int H)
{
    __shared__ __align__(16) unsigned short Ks[2][64][72];   // [buf][key][d]
    __shared__ __align__(16) unsigned short Vs[2][64][72];   // [buf][d][key]

    const int tid  = threadIdx.x;
    const int wave = tid >> 6;
    const int lane = tid & 63;
    const int ln15 = lane & 15;
    const int kg   = lane >> 4;
    const int sA   = blockIdx.x;              // 0..15
    const int sB   = (T >> 6) - 1 - sA;       // 31..16
    const int kmax = sB;
    const int bh   = blockIdx.y;
    const int b    = bh >> 4, h = bh & 15;
    const size_t base  = (size_t)bh * T * 64;
    const size_t vbase = (size_t)bh * 64 * T;
    const int q_loc = wave * 16 + ln15;       // query row within strip

    bf16x8 qf[2][2];
    {
        const unsigned short* QrA = Q + base + (size_t)(sA * 64 + q_loc) * 64;
        const unsigned short* QrB = Q + base + (size_t)(sB * 64 + q_loc) * 64;
        qf[0][0] = *(const bf16x8*)(QrA + kg * 8);
        qf[0][1] = *(const bf16x8*)(QrA + 32 + kg * 8);
        qf[1][0] = *(const bf16x8*)(QrB + kg * 8);
        qf[1][1] = *(const bf16x8*)(QrB + 32 + kg * 8);
    }

    bf16x8 ones;
    {
        const short o = (ln15 == 0) ? (short)0x3F80 : (short)0;
#pragma unroll
        for (int j = 0; j < 8; ++j) ones[j] = o;
    }

    f32x4 o_acc[2][4];
#pragma unroll
    for (int s = 0; s < 2; ++s)
#pragma unroll
        for (int dt = 0; dt < 4; ++dt) o_acc[s][dt] = (f32x4){0.f, 0.f, 0.f, 0.f};
    f32x4 acc_l[2] = {(f32x4){0.f, 0.f, 0.f, 0.f}, (f32x4){0.f, 0.f, 0.f, 0.f}};

    const int sky = tid >> 3;             // 0..31
    const int sd  = (tid & 7) * 8;

    bf16x8 pk0, pk1, pv0, pv1;
    pk0 = *(const bf16x8*)(Km + base + (size_t)sky * 64 + sd);
    pk1 = *(const bf16x8*)(Km + base + (size_t)(sky + 32) * 64 + sd);
    pv0 = *(const bf16x8*)(Vtg + vbase + (size_t)sky * T + sd);
    pv1 = *(const bf16x8*)(Vtg + vbase + (size_t)(sky + 32) * T + sd);

    for (int kb = 0; kb <= kmax; ++kb) {
        const int bufi = kb & 1;
        *(bf16x8*)&Ks[bufi][sky][sd]      = pk0;
        *(bf16x8*)&Ks[bufi][sky + 32][sd] = pk1;
        *(bf16x8*)&Vs[bufi][sky][sd]      = pv0;
        *(bf16x8*)&Vs[bufi][sky + 32][sd] = pv1;
        if (kb < kmax) {
            const int kn = (kb + 1) * 64;
            pk0 = *(const bf16x8*)(Km + base + (size_t)(kn + sky) * 64 + sd);
            pk1 = *(const bf16x8*)(Km + base + (size_t)(kn + sky + 32) * 64 + sd);
            pv0 = *(const bf16x8*)(Vtg + vbase + (size_t)sky * T + kn + sd);
            pv1 = *(const bf16x8*)(Vtg + vbase + (size_t)(sky + 32) * T + kn + sd);
        }
        __syncthreads();

        const bool doA = (kb <= sA);

        f32x4 srB[4], srA[4];
        __builtin_amdgcn_s_setprio(1);
#pragma unroll
        for (int kt = 0; kt < 4; ++kt) {
            bf16x8 kf0 = *(const bf16x8*)&Ks[bufi][kt * 16 + ln15][kg * 8];
            bf16x8 kf1 = *(const bf16x8*)&Ks[bufi][kt * 16 + ln15][32 + kg * 8];
            f32x4 a = (f32x4){0.f, 0.f, 0.f, 0.f};
            a = __builtin_amdgcn_mfma_f32_16x16x32_bf16(kf0, qf[1][0], a, 0, 0, 0);
            a = __builtin_amdgcn_mfma_f32_16x16x32_bf16(kf1, qf[1][1], a, 0, 0, 0);
            srB[kt] = a;
            if (doA) {
                f32x4 c = (f32x4){0.f, 0.f, 0.f, 0.f};
                c = __builtin_amdgcn_mfma_f32_16x16x32_bf16(kf0, qf[0][0], c, 0, 0, 0);
                c = __builtin_amdgcn_mfma_f32_16x16x32_bf16(kf1, qf[0][1], c, 0, 0, 0);
                srA[kt] = c;
            }
        }
        __builtin_amdgcn_s_setprio(0);

        bf16x8 pfB0, pfB1, pfA0, pfA1;
        softmax_tile(srB, kb == sB, q_loc, kg, pfB0, pfB1, acc_l[1], ones);
        if (doA)
            softmax_tile(srA, kb == sA, q_loc, kg, pfA0, pfA1, acc_l[0], ones);

        __builtin_amdgcn_s_setprio(1);
#pragma unroll
        for (int dt = 0; dt < 4; ++dt) {
            bf16x8 vf0 = *(const bf16x8*)&Vs[bufi][dt * 16 + ln15][kg * 8];
            bf16x8 vf1 = *(const bf16x8*)&Vs[bufi][dt * 16 + ln15][32 + kg * 8];
            o_acc[1][dt] = __builtin_amdgcn_mfma_f32_16x16x32_bf16(pfB0, vf0, o_acc[1][dt], 0, 0, 0);
            o_acc[1][dt] = __builtin_amdgcn_mfma_f32_16x16x32_bf16(pfB1, vf1, o_acc[1][dt], 0, 0, 0);
            if (doA) {
                o_acc[0][dt] = __builtin_amdgcn_mfma_f32_16x16x32_bf16(pfA0, vf0, o_acc[0][dt], 0, 0, 0);
                o_acc[0][dt] = __builtin_amdgcn_mfma_f32_16x16x32_bf16(pfA1, vf1, o_acc[0][dt], 0, 0, 0);
            }
        }
        __builtin_amdgcn_s_setprio(0);
    }

    // normalize; l for row kg*4+r sits in lane kg*16 (col 0)
#pragma unroll
    for (int s = 0; s < 2; ++s) {
        const int qb = (s == 0 ? sA : sB) * 64;
        float inv[4];
#pragma unroll
        for (int r = 0; r < 4; ++r)
            inv[r] = 1.0f / __shfl(acc_l[s][r], lane & 48, 64);
#pragma unroll
        for (int dt = 0; dt < 4; ++dt)
#pragma unroll
            for (int r = 0; r < 4; ++r) {
                const int t = qb + wave * 16 + kg * 4 + r;
                const int d = dt * 16 + ln15;
                O[(size_t)(b * T + t) * (H * 64) + h * 64 + d] =
                    f2bf(o_acc[s][dt][r] * inv[r]);
            }
    }
}

extern "C" void kernel_launch(void* const* d_in, const int* in_sizes, int n_in,
                              void* d_out, int out_size, void* d_ws, size_t ws_size,
                              hipStream_t stream)
{
    const int B = 2, T = 2048, E = 1024, H = 16;
    const int M = B * T;  // 4096

    const float* x  = (const float*)d_in[0];
    const float* Wq = (const float*)d_in[1];
    const float* Wk = (const float*)d_in[2];
    const float* Wv = (const float*)d_in[3];
    const float* Wo = (const float*)d_in[4];
    const float* bo = (const float*)d_in[5];
    float* out = (float*)d_out;

    // workspace (bf16): xb 8MB, WqkvT 6MB, WoT 2MB, q/k/vT 8MB x3, ao 8MB
    unsigned short* xb     = (unsigned short*)d_ws;
    unsigned short* WqkvT  = xb + (size_t)M * E;            // [3072][1024]
    unsigned short* WoT    = WqkvT + (size_t)3 * E * E;     // [1024][1024]
    unsigned short* q      = WoT + (size_t)E * E;           // [BH][T][64]
    unsigned short* k      = q + (size_t)M * E;
    unsigned short* vT     = k + (size_t)M * E;             // [BH][64][T]
    unsigned short* ao     = vT + (size_t)M * E;            // [M][E]

    // fused convert + 4x weight transpose (1 launch)
    prep<<<8192, 256, 0, stream>>>(x, Wq, Wk, Wv, Wo, xb, WqkvT, WoT);

    // fused QKV projection: [4096,1024] @ [1024,3072]; V written transposed
    dim3 g1(M / 128, 3 * E / 128);
    gemm128<1><<<g1, 256, 0, stream>>>(xb, WqkvT, nullptr, nullptr, q, k, vT,
                                       M, 3 * E, E);

    // flash attention: 16 balanced strip-pair blocks x 32 bh
    dim3 ag(T / 128, B * H);
    flash_attn<<<ag, 256, 0, stream>>>(q, k, vT, ao, T, H);

    dim3 g2(M / 128, E / 128);
    gemm128<0><<<g2, 256, 0, stream>>>(ao, WoT, bo, out, nullptr, nullptr, nullptr,
                                       M, E, E);
}

// Round 8
// 178.996 us; speedup vs baseline: 1.4764x; 1.0216x over previous
//
#include <hip/hip_runtime.h>
#include <hip/hip_bf16.h>

typedef __attribute__((ext_vector_type(8))) short bf16x8;
typedef __attribute__((ext_vector_type(4))) float f32x4;
typedef __attribute__((ext_vector_type(4))) unsigned short u16x4;

__device__ __forceinline__ unsigned short f2bf(float f) {
    union { float f; unsigned int i; } x; x.f = f;
    unsigned int lsb = (x.i >> 16) & 1u;
    x.i += 0x7fffu + lsb;  // round-to-nearest-even
    return (unsigned short)(x.i >> 16);
}

// async global->LDS DMA, 16B per lane; lds ptr wave-uniform, HW adds lane*16
__device__ __forceinline__ void gl_lds16(const unsigned short* g, unsigned short* l) {
    __builtin_amdgcn_global_load_lds(
        (const __attribute__((address_space(1))) void*)g,
        (__attribute__((address_space(3))) void*)l, 16, 0, 0);
}

__device__ __forceinline__ unsigned int cvt_pk_bf16(float lo, float hi) {
    unsigned int d;
    asm("v_cvt_pk_bf16_f32 %0, %1, %2" : "=v"(d) : "v"(lo), "v"(hi));
    return d;
}

// In-register 16x32 C-fragment transpose -> A-frag/store layout (attn-verified).
// Input: pa = C-frag rows 0..15 of a 32-row span (per-lane row=kg*4+r, col=ln15),
//        pb = rows 16..31. Output: lane (kg,ln15) holds bf16 of rows kg*8..kg*8+7
// at fixed col=ln15 -> one contiguous 16B run along the row direction.
__device__ __forceinline__ bf16x8 pf_build_s(f32x4 pa, f32x4 pb, float s) {
    unsigned int E0 = cvt_pk_bf16(pa[0] * s, pa[1] * s);
    unsigned int O0 = cvt_pk_bf16(pa[2] * s, pa[3] * s);
    unsigned int E1 = cvt_pk_bf16(pb[0] * s, pb[1] * s);
    unsigned int O1 = cvt_pk_bf16(pb[2] * s, pb[3] * s);
    asm("v_permlane32_swap_b32 %0, %1" : "+v"(E0), "+v"(E1));
    asm("v_permlane32_swap_b32 %0, %1" : "+v"(O0), "+v"(O1));
    asm("v_permlane16_swap_b32 %0, %1" : "+v"(E0), "+v"(E1));
    asm("v_permlane16_swap_b32 %0, %1" : "+v"(O0), "+v"(O1));
    union { unsigned int u[4]; bf16x8 v; } r;
    r.u[0] = E0; r.u[1] = O0; r.u[2] = E1; r.u[3] = O1;
    return r.v;
}

// ---------------------------------------------------------------------------
// fused preprocessing: blocks [0,4096) = fp32->bf16 convert of x (x4 vec);
// blocks [4096,8192) = 32x32 transpose+convert of the 4 weight matrices.
// ---------------------------------------------------------------------------
__global__ __launch_bounds__(256) void prep(
    const float* __restrict__ x,
    const float* __restrict__ Wq, const float* __restrict__ Wk,
    const float* __restrict__ Wv, const float* __restrict__ Wo,
    unsigned short* __restrict__ xb,
    unsigned short* __restrict__ WqkvT, unsigned short* __restrict__ WoT)
{
    const int E = 1024;
    const int bid = blockIdx.x;
    __shared__ float t[32][33];

    if (bid < 4096) {                       // x convert: 4096*256*4 = 4M elems
        int i = bid * 256 + threadIdx.x;
        f32x4 v = ((const f32x4*)x)[i];
        u16x4 o;
#pragma unroll
        for (int j = 0; j < 4; ++j) o[j] = f2bf(v[j]);
        ((u16x4*)xb)[i] = o;
        return;
    }
    const int r = bid - 4096;
    const int which = r >> 10;              // 0..3 : Wq,Wk,Wv,Wo
    const int sub = r & 1023;
    const float* src = which == 0 ? Wq : which == 1 ? Wk : which == 2 ? Wv : Wo;
    unsigned short* dst = which == 3 ? WoT : WqkvT + (size_t)which * E * E;

    const int tx = threadIdx.x & 31, ty = threadIdx.x >> 5;  // ty 0..7
    const int n0 = (sub & 31) * 32, k0 = (sub >> 5) * 32;
#pragma unroll
    for (int i = 0; i < 4; ++i)
        t[ty + 8 * i][tx] = src[(size_t)(k0 + ty + 8 * i) * E + n0 + tx];
    __syncthreads();
#pragma unroll
    for (int i = 0; i < 4; ++i)
        dst[(size_t)(n0 + ty + 8 * i) * E + k0 + tx] = f2bf(t[tx][ty + 8 * i]);
}

// ---------------------------------------------------------------------------
// m97-style GEMM (QKV): C = A[M,K] @ BT[N,K]^T, bf16 in, fp32 acc. 128x128
// tile, BK=32, 256 thr = 4 waves 2x2; 16 MFMA + 8 ds_read_b128 per
// K-step/wave; staging via global_load_lds dwordx4. UNCHANGED from R3/R7.
//
// PERM=1 only now (out-proj moved to gemm_op): unswapped mfma(af,bw).
// Epilogue: q/k scalar u16 stores; v section uses pf_build -> writes V
// TRANSPOSED [bh][d][t] directly.
// ---------------------------------------------------------------------------
template <int PERM>
__global__ __launch_bounds__(256) void gemm128(
    const unsigned short* __restrict__ A,
    const unsigned short* __restrict__ BT,
    const float* __restrict__ bias,
    float* __restrict__ Cf,
    unsigned short* __restrict__ q_out,
    unsigned short* __restrict__ k_out,
    unsigned short* __restrict__ v_out,   // [bh][64][T] transposed
    int M, int N, int K)
{
    __shared__ __align__(16) unsigned short As[128 * 32];
    __shared__ __align__(16) unsigned short Bs[128 * 32];

    const int tid  = threadIdx.x;
    const int wave = tid >> 6;
    const int lane = tid & 63;
    const int ln15 = lane & 15;
    const int kg   = lane >> 4;
    const int bm = blockIdx.x * 128, bn = blockIdx.y * 128;
    const int wm = (wave >> 1) * 64, wn = (wave & 1) * 64;

    f32x4 acc[4][4];
#pragma unroll
    for (int i = 0; i < 4; ++i)
#pragma unroll
        for (int j = 0; j < 4; ++j) acc[i][j] = (f32x4){0.f, 0.f, 0.f, 0.f};

    const int sr = wave * 32 + (lane >> 2);
    const int sc = (lane & 3) * 8;

    for (int k0 = 0; k0 < K; k0 += 32) {
        gl_lds16(A  + (size_t)(bm + sr)      * K + k0 + sc, As + wave * 1024);
        gl_lds16(A  + (size_t)(bm + sr + 16) * K + k0 + sc, As + wave * 1024 + 512);
        gl_lds16(BT + (size_t)(bn + sr)      * K + k0 + sc, Bs + wave * 1024);
        gl_lds16(BT + (size_t)(bn + sr + 16) * K + k0 + sc, Bs + wave * 1024 + 512);
        __syncthreads();

        bf16x8 af[4], bw[4];
#pragma unroll
        for (int mt = 0; mt < 4; ++mt)
            af[mt] = *(const bf16x8*)&As[(wm + mt * 16 + ln15) * 32 + kg * 8];
#pragma unroll
        for (int nt = 0; nt < 4; ++nt)
            bw[nt] = *(const bf16x8*)&Bs[(wn + nt * 16 + ln15) * 32 + kg * 8];
        if (PERM == 0) {   // compile-time: C^T fragments (unused instantiation)
#pragma unroll
            for (int mt = 0; mt < 4; ++mt)
#pragma unroll
                for (int nt = 0; nt < 4; ++nt)
                    acc[mt][nt] = __builtin_amdgcn_mfma_f32_16x16x32_bf16(
                        bw[nt], af[mt], acc[mt][nt], 0, 0, 0);
        } else {           // compile-time: C fragments
#pragma unroll
            for (int mt = 0; mt < 4; ++mt)
#pragma unroll
                for (int nt = 0; nt < 4; ++nt)
                    acc[mt][nt] = __builtin_amdgcn_mfma_f32_16x16x32_bf16(
                        af[mt], bw[nt], acc[mt][nt], 0, 0, 0);
        }
        __syncthreads();
    }

    if (PERM == 0) {
#pragma unroll
        for (int mt = 0; mt < 4; ++mt) {
            const int row = bm + wm + mt * 16 + ln15;
#pragma unroll
            for (int nt = 0; nt < 4; ++nt) {
                const int c0 = bn + wn + nt * 16 + kg * 4;
                f32x4 bv = *(const f32x4*)(bias + c0);
                f32x4 o;
#pragma unroll
                for (int r = 0; r < 4; ++r) o[r] = acc[mt][nt][r] + bv[r];
                *(f32x4*)(Cf + (size_t)row * N + c0) = o;
            }
        }
    } else {
        const int sec = bn >> 10;
        if (sec < 2) {
            // unswapped frags; per-lane col=ln15 fixed, rows vary -> scalar
            // u16 stores
            unsigned short* dst = sec == 0 ? q_out : k_out;
            const float scale = sec == 0 ? 0.125f : 1.0f;  // q pre-scale (pow2)
#pragma unroll
            for (int nt = 0; nt < 4; ++nt) {
                const int col = bn + wn + nt * 16 + ln15;
                const int h = (col >> 6) & 15, d = col & 63;
#pragma unroll
                for (int mt = 0; mt < 4; ++mt) {
#pragma unroll
                    for (int r = 0; r < 4; ++r) {
                        const int row = bm + wm + mt * 16 + kg * 4 + r;
                        const int b = row >> 11, t = row & 2047;
                        dst[((size_t)(b * 16 + h) * 2048 + t) * 64 + d] =
                            f2bf(acc[mt][nt][r] * scale);
                    }
                }
            }
        } else {
            // unswapped; pf_build over mt-pairs -> lane holds col d=ln15 fixed,
            // rows t contiguous -> writes vT[bh][d][t] directly (T=2048)
#pragma unroll
            for (int nt = 0; nt < 4; ++nt) {
                const int c = bn + wn + nt * 16 + ln15;
                const int h = (c >> 6) & 15, d = c & 63;
#pragma unroll
                for (int mp = 0; mp < 2; ++mp) {
                    const int t0 = bm + wm + mp * 32 + kg * 8;
                    const int b = t0 >> 11, t = t0 & 2047;
                    bf16x8 pf = pf_build_s(acc[2 * mp][nt], acc[2 * mp + 1][nt], 1.0f);
                    *(bf16x8*)(v_out + ((size_t)(b * 16 + h) * 64 + d) * 2048 + t) = pf;
                }
            }
        }
    }
}

// ---------------------------------------------------------------------------
// out-projection GEMM, 128x64 tile: Cf = A[M,K] @ BT[N,K]^T + bias (fp32 out).
//
// R7 accounting: out-proj at 128x128 tiles had grid (32,8) = 256 blocks =
// EXACTLY 1 block/CU -- zero co-residency, every staging drain exposed,
// ~30 us (~260 TF) and invisible below every top-5 cutoff. Halving the
// N-tile doubles the grid: (32,16) = 512 blocks = 2 blocks/CU, so two
// blocks interleave each other's barrier/staging stalls (the mechanism that
// puts QKV at 3/CU / 590 TF). Same m97 schedule otherwise: gl_lds16
// staging, BK=32, swapped mfma(bw,af) = C^T frags (single-path loop),
// f32x4 bias+store epilogue. Per wave: 64x32 out, 8 MFMA + 6 ds_read/iter.
// Standalone kernel so gemm128<1>'s codegen is untouched.
// ---------------------------------------------------------------------------
__global__ __launch_bounds__(256) void gemm_op(
    const unsigned short* __restrict__ A,
    const unsigned short* __restrict__ BT,
    const float* __restrict__ bias,
    float* __restrict__ Cf,
    int M, int N, int K)
{
    __shared__ __align__(16) unsigned short As[128 * 32];
    __shared__ __align__(16) unsigned short Bs[64 * 32];

    const int tid  = threadIdx.x;
    const int wave = tid >> 6;
    const int lane = tid & 63;
    const int ln15 = lane & 15;
    const int kg   = lane >> 4;
    const int bm = blockIdx.x * 128, bn = blockIdx.y * 64;
    const int wm = (wave >> 1) * 64, wn = (wave & 1) * 32;

    f32x4 acc[4][2];
#pragma unroll
    for (int i = 0; i < 4; ++i)
#pragma unroll
        for (int j = 0; j < 2; ++j) acc[i][j] = (f32x4){0.f, 0.f, 0.f, 0.f};

    const int sr  = wave * 32 + (lane >> 2);   // A stage rows (2 calls: +0,+16)
    const int srB = wave * 16 + (lane >> 2);   // B stage rows (1 call)
    const int sc  = (lane & 3) * 8;

    for (int k0 = 0; k0 < K; k0 += 32) {
        gl_lds16(A  + (size_t)(bm + sr)      * K + k0 + sc, As + wave * 1024);
        gl_lds16(A  + (size_t)(bm + sr + 16) * K + k0 + sc, As + wave * 1024 + 512);
        gl_lds16(BT + (size_t)(bn + srB)     * K + k0 + sc, Bs + wave * 512);
        __syncthreads();

        bf16x8 af[4], bw[2];
#pragma unroll
        for (int mt = 0; mt < 4; ++mt)
            af[mt] = *(const bf16x8*)&As[(wm + mt * 16 + ln15) * 32 + kg * 8];
#pragma unroll
        for (int nt = 0; nt < 2; ++nt)
            bw[nt] = *(const bf16x8*)&Bs[(wn + nt * 16 + ln15) * 32 + kg * 8];
#pragma unroll
        for (int mt = 0; mt < 4; ++mt)
#pragma unroll
            for (int nt = 0; nt < 2; ++nt)
                acc[mt][nt] = __builtin_amdgcn_mfma_f32_16x16x32_bf16(
                    bw[nt], af[mt], acc[mt][nt], 0, 0, 0);
        __syncthreads();
    }

    // swapped: acc[mt][nt][r] = C[row=bm+wm+mt*16+ln15][col=bn+wn+nt*16+kg*4+r]
#pragma unroll
    for (int mt = 0; mt < 4; ++mt) {
        const int row = bm + wm + mt * 16 + ln15;
#pragma unroll
        for (int nt = 0; nt < 2; ++nt) {
            const int c0 = bn + wn + nt * 16 + kg * 4;
            f32x4 bv = *(const f32x4*)(bias + c0);
            f32x4 o;
#pragma unroll
            for (int r = 0; r < 4; ++r) o[r] = acc[mt][nt][r] + bv[r];
            *(f32x4*)(Cf + (size_t)row * N + c0) = o;
        }
    }
}

// mask (diagonal block) + exp + in-register transpose + row-sum accumulate
__device__ __forceinline__ void softmax_tile(
    f32x4 sr[4], bool diag, int q_loc, int kg,
    bf16x8& pf0, bf16x8& pf1, f32x4& accl, bf16x8 ones)
{
    if (diag) {
#pragma unroll
        for (int kt = 0; kt < 4; ++kt)
#pragma unroll
            for (int r = 0; r < 4; ++r)
                if (kt * 16 + kg * 4 + r > q_loc) sr[kt][r] = -1e30f;
    }
    f32x4 pe[4];
#pragma unroll
    for (int kt = 0; kt < 4; ++kt)
#pragma unroll
        for (int r = 0; r < 4; ++r) pe[kt][r] = __expf(sr[kt][r]);
    pf0 = pf_build_s(pe[0], pe[1], 1.0f);
    pf1 = pf_build_s(pe[2], pe[3], 1.0f);
    accl = __builtin_amdgcn_mfma_f32_16x16x32_bf16(pf0, ones, accl, 0, 0, 0);
    accl = __builtin_amdgcn_mfma_f32_16x16x32_bf16(pf1, ones, accl, 0, 0, 0);
}

// ---------------------------------------------------------------------------
// MFMA flash attention v6+T5 (causal). UNCHANGED from R7 (182.9 us verified).
// Paired strips (sA=x, sB=31-x, 33 iters balanced); K/V staged once, shared;
// double-buffered LDS; ONE barrier/iter; register prefetch; swapped QK^T +
// in-register P transpose; s_setprio(1) around MFMA clusters.
// ---------------------------------------------------------------------------
__global__ __launch_bounds__(256) void flash_attn(
    const unsigned short* __restrict__ Q,
    const unsigned short* __restrict__ Km,
    const unsigned short* __restrict__ Vtg,
    unsigned short* __restrict__ O,
    int T, int H)
{
    __shared__ __align__(16) unsigned short Ks[2][64][72];   // [buf][key][d]
    __shared__ __align__(16) unsigned short Vs[2][64][72];   // [buf][d][key]

    const int tid  = threadIdx.x;
    const int wave = tid >> 6;
    const int lane = tid & 63;
    const int ln15 = lane & 15;
    const int kg   = lane >> 4;
    const int sA   = blockIdx.x;              // 0..15
    const int sB   = (T >> 6) - 1 - sA;       // 31..16
    const int kmax = sB;
    const int bh   = blockIdx.y;
    const int b    = bh >> 4, h = bh & 15;
    const size_t base  = (size_t)bh * T * 64;
    const size_t vbase = (size_t)bh * 64 * T;
    const int q_loc = wave * 16 + ln15;       // query row within strip

    bf16x8 qf[2][2];
    {
        const unsigned short* QrA = Q + base + (size_t)(sA * 64 + q_loc) * 64;
        const unsigned short* QrB = Q + base + (size_t)(sB * 64 + q_loc) * 64;
        qf[0][0] = *(const bf16x8*)(QrA + kg * 8);
        qf[0][1] = *(const bf16x8*)(QrA + 32 + kg * 8);
        qf[1][0] = *(const bf16x8*)(QrB + kg * 8);
        qf[1][1] = *(const bf16x8*)(QrB + 32 + kg * 8);
    }

    bf16x8 ones;
    {
        const short o = (ln15 == 0) ? (short)0x3F80 : (short)0;
#pragma unroll
        for (int j = 0; j < 8; ++j) ones[j] = o;
    }

    f32x4 o_acc[2][4];
#pragma unroll
    for (int s = 0; s < 2; ++s)
#pragma unroll
        for (int dt = 0; dt < 4; ++dt) o_acc[s][dt] = (f32x4){0.f, 0.f, 0.f, 0.f};
    f32x4 acc_l[2] = {(f32x4){0.f, 0.f, 0.f, 0.f}, (f32x4){0.f, 0.f, 0.f, 0.f}};

    const int sky = tid >> 3;             // 0..31
    const int sd  = (tid & 7) * 8;

    bf16x8 pk0, pk1, pv0, pv1;
    pk0 = *(const bf16x8*)(Km + base + (size_t)sky * 64 + sd);
    pk1 = *(const bf16x8*)(Km + base + (size_t)(sky + 32) * 64 + sd);
    pv0 = *(const bf16x8*)(Vtg + vbase + (size_t)sky * T + sd);
    pv1 = *(const bf16x8*)(Vtg + vbase + (size_t)(sky + 32) * T + sd);

    for (int kb = 0; kb <= kmax; ++kb) {
        const int bufi = kb & 1;
        *(bf16x8*)&Ks[bufi][sky][sd]      = pk0;
        *(bf16x8*)&Ks[bufi][sky + 32][sd] = pk1;
        *(bf16x8*)&Vs[bufi][sky][sd]      = pv0;
        *(bf16x8*)&Vs[bufi][sky + 32][sd] = pv1;
        if (kb < kmax) {
            const int kn = (kb + 1) * 64;
            pk0 = *(const bf16x8*)(Km + base + (size_t)(kn + sky) * 64 + sd);
            pk1 = *(const bf16x8*)(Km + base + (size_t)(kn + sky + 32) * 64 + sd);
            pv0 = *(const bf16x8*)(Vtg + vbase + (size_t)sky * T + kn + sd);
            pv1 = *(const bf16x8*)(Vtg + vbase + (size_t)(sky + 32) * T + kn + sd);
        }
        __syncthreads();

        const bool doA = (kb <= sA);

        f32x4 srB[4], srA[4];
        __builtin_amdgcn_s_setprio(1);
#pragma unroll
        for (int kt = 0; kt < 4; ++kt) {
            bf16x8 kf0 = *(const bf16x8*)&Ks[bufi][kt * 16 + ln15][kg * 8];
            bf16x8 kf1 = *(const bf16x8*)&Ks[bufi][kt * 16 + ln15][32 + kg * 8];
            f32x4 a = (f32x4){0.f, 0.f, 0.f, 0.f};
            a = __builtin_amdgcn_mfma_f32_16x16x32_bf16(kf0, qf[1][0], a, 0, 0, 0);
            a = __builtin_amdgcn_mfma_f32_16x16x32_bf16(kf1, qf[1][1], a, 0, 0, 0);
            srB[kt] = a;
            if (doA) {
                f32x4 c = (f32x4){0.f, 0.f, 0.f, 0.f};
                c = __builtin_amdgcn_mfma_f32_16x16x32_bf16(kf0, qf[0][0], c, 0, 0, 0);
                c = __builtin_amdgcn_mfma_f32_16x16x32_bf16(kf1, qf[0][1], c, 0, 0, 0);
                srA[kt] = c;
            }
        }
        __builtin_amdgcn_s_setprio(0);

        bf16x8 pfB0, pfB1, pfA0, pfA1;
        softmax_tile(srB, kb == sB, q_loc, kg, pfB0, pfB1, acc_l[1], ones);
        if (doA)
            softmax_tile(srA, kb == sA, q_loc, kg, pfA0, pfA1, acc_l[0], ones);

        __builtin_amdgcn_s_setprio(1);
#pragma unroll
        for (int dt = 0; dt < 4; ++dt) {
            bf16x8 vf0 = *(const bf16x8*)&Vs[bufi][dt * 16 + ln15][kg * 8];
            bf16x8 vf1 = *(const bf16x8*)&Vs[bufi][dt * 16 + ln15][32 + kg * 8];
            o_acc[1][dt] = __builtin_amdgcn_mfma_f32_16x16x32_bf16(pfB0, vf0, o_acc[1][dt], 0, 0, 0);
            o_acc[1][dt] = __builtin_amdgcn_mfma_f32_16x16x32_bf16(pfB1, vf1, o_acc[1][dt], 0, 0, 0);
            if (doA) {
                o_acc[0][dt] = __builtin_amdgcn_mfma_f32_16x16x32_bf16(pfA0, vf0, o_acc[0][dt], 0, 0, 0);
                o_acc[0][dt] = __builtin_amdgcn_mfma_f32_16x16x32_bf16(pfA1, vf1, o_acc[0][dt], 0, 0, 0);
            }
        }
        __builtin_amdgcn_s_setprio(0);
    }

    // normalize; l for row kg*4+r sits in lane kg*16 (col 0)
#pragma unroll
    for (int s = 0; s < 2; ++s) {
        const int qb = (s == 0 ? sA : sB) * 64;
        float inv[4];
#pragma unroll
        for (int r = 0; r < 4; ++r)
            inv[r] = 1.0f / __shfl(acc_l[s][r], lane & 48, 64);
#pragma unroll
        for (int dt = 0; dt < 4; ++dt)
#pragma unroll
            for (int r = 0; r < 4; ++r) {
                const int t = qb + wave * 16 + kg * 4 + r;
                const int d = dt * 16 + ln15;
                O[(size_t)(b * T + t) * (H * 64) + h * 64 + d] =
                    f2bf(o_acc[s][dt][r] * inv[r]);
            }
    }
}

extern "C" void kernel_launch(void* const* d_in, const int* in_sizes, int n_in,
                              void* d_out, int out_size, void* d_ws, size_t ws_size,
                              hipStream_t stream)
{
    const int B = 2, T = 2048, E = 1024, H = 16;
    const int M = B * T;  // 4096

    const float* x  = (const float*)d_in[0];
    const float* Wq = (const float*)d_in[1];
    const float* Wk = (const float*)d_in[2];
    const float* Wv = (const float*)d_in[3];
    const float* Wo = (const float*)d_in[4];
    const float* bo = (const float*)d_in[5];
    float* out = (float*)d_out;

    // workspace (bf16): xb 8MB, WqkvT 6MB, WoT 2MB, q/k/vT 8MB x3, ao 8MB
    unsigned short* xb     = (unsigned short*)d_ws;
    unsigned short* WqkvT  = xb + (size_t)M * E;            // [3072][1024]
    unsigned short* WoT    = WqkvT + (size_t)3 * E * E;     // [1024][1024]
    unsigned short* q      = WoT + (size_t)E * E;           // [BH][T][64]
    unsigned short* k      = q + (size_t)M * E;
    unsigned short* vT     = k + (size_t)M * E;             // [BH][64][T]
    unsigned short* ao     = vT + (size_t)M * E;            // [M][E]

    // fused convert + 4x weight transpose (1 launch)
    prep<<<8192, 256, 0, stream>>>(x, Wq, Wk, Wv, Wo, xb, WqkvT, WoT);

    // fused QKV projection: [4096,1024] @ [1024,3072]; V written transposed
    dim3 g1(M / 128, 3 * E / 128);
    gemm128<1><<<g1, 256, 0, stream>>>(xb, WqkvT, nullptr, nullptr, q, k, vT,
                                       M, 3 * E, E);

    // flash attention: 16 balanced strip-pair blocks x 32 bh
    dim3 ag(T / 128, B * H);
    flash_attn<<<ag, 256, 0, stream>>>(q, k, vT, ao, T, H);

    // out-projection: 128x64 tiles -> 512 blocks = 2/CU (was 256 = 1/CU)
    dim3 g2(M / 128, E / 64);
    gemm_op<<<g2, 256, 0, stream>>>(ao, WoT, bo, out, M, E, E);
}

// Round 10
// 176.756 us; speedup vs baseline: 1.4951x; 1.0127x over previous
//
#include <hip/hip_runtime.h>
#include <hip/hip_bf16.h>

typedef __attribute__((ext_vector_type(8))) short bf16x8;
typedef __attribute__((ext_vector_type(4))) float f32x4;
typedef __attribute__((ext_vector_type(4))) unsigned short u16x4;

__device__ __forceinline__ unsigned short f2bf(float f) {
    union { float f; unsigned int i; } x; x.f = f;
    unsigned int lsb = (x.i >> 16) & 1u;
    x.i += 0x7fffu + lsb;  // round-to-nearest-even
    return (unsigned short)(x.i >> 16);
}

// async global->LDS DMA, 16B per lane; lds ptr wave-uniform, HW adds lane*16
__device__ __forceinline__ void gl_lds16(const unsigned short* g, unsigned short* l) {
    __builtin_amdgcn_global_load_lds(
        (const __attribute__((address_space(1))) void*)g,
        (__attribute__((address_space(3))) void*)l, 16, 0, 0);
}

__device__ __forceinline__ unsigned int cvt_pk_bf16(float lo, float hi) {
    unsigned int d;
    asm("v_cvt_pk_bf16_f32 %0, %1, %2" : "=v"(d) : "v"(lo), "v"(hi));
    return d;
}

// In-register 16x32 C-fragment transpose -> A-frag/store layout (attn-verified).
// Input: pa = C-frag rows 0..15 of a 32-row span (per-lane row=kg*4+r, col=ln15),
//        pb = rows 16..31. Output: lane (kg,ln15) holds bf16 of rows kg*8..kg*8+7
// at fixed col=ln15 -> one contiguous 16B run along the row direction.
__device__ __forceinline__ bf16x8 pf_build_s(f32x4 pa, f32x4 pb, float s) {
    unsigned int E0 = cvt_pk_bf16(pa[0] * s, pa[1] * s);
    unsigned int O0 = cvt_pk_bf16(pa[2] * s, pa[3] * s);
    unsigned int E1 = cvt_pk_bf16(pb[0] * s, pb[1] * s);
    unsigned int O1 = cvt_pk_bf16(pb[2] * s, pb[3] * s);
    asm("v_permlane32_swap_b32 %0, %1" : "+v"(E0), "+v"(E1));
    asm("v_permlane32_swap_b32 %0, %1" : "+v"(O0), "+v"(O1));
    asm("v_permlane16_swap_b32 %0, %1" : "+v"(E0), "+v"(E1));
    asm("v_permlane16_swap_b32 %0, %1" : "+v"(O0), "+v"(O1));
    union { unsigned int u[4]; bf16x8 v; } r;
    r.u[0] = E0; r.u[1] = O0; r.u[2] = E1; r.u[3] = O1;
    return r.v;
}

// ---------------------------------------------------------------------------
// fused preprocessing: blocks [0,4096) = fp32->bf16 convert of x (x4 vec);
// blocks [4096,8192) = 32x32 transpose+convert of the 4 weight matrices.
// ---------------------------------------------------------------------------
__global__ __launch_bounds__(256) void prep(
    const float* __restrict__ x,
    const float* __restrict__ Wq, const float* __restrict__ Wk,
    const float* __restrict__ Wv, const float* __restrict__ Wo,
    unsigned short* __restrict__ xb,
    unsigned short* __restrict__ WqkvT, unsigned short* __restrict__ WoT)
{
    const int E = 1024;
    const int bid = blockIdx.x;
    __shared__ float t[32][33];

    if (bid < 4096) {                       // x convert: 4096*256*4 = 4M elems
        int i = bid * 256 + threadIdx.x;
        f32x4 v = ((const f32x4*)x)[i];
        u16x4 o;
#pragma unroll
        for (int j = 0; j < 4; ++j) o[j] = f2bf(v[j]);
        ((u16x4*)xb)[i] = o;
        return;
    }
    const int r = bid - 4096;
    const int which = r >> 10;              // 0..3 : Wq,Wk,Wv,Wo
    const int sub = r & 1023;
    const float* src = which == 0 ? Wq : which == 1 ? Wk : which == 2 ? Wv : Wo;
    unsigned short* dst = which == 3 ? WoT : WqkvT + (size_t)which * E * E;

    const int tx = threadIdx.x & 31, ty = threadIdx.x >> 5;  // ty 0..7
    const int n0 = (sub & 31) * 32, k0 = (sub >> 5) * 32;
#pragma unroll
    for (int i = 0; i < 4; ++i)
        t[ty + 8 * i][tx] = src[(size_t)(k0 + ty + 8 * i) * E + n0 + tx];
    __syncthreads();
#pragma unroll
    for (int i = 0; i < 4; ++i)
        dst[(size_t)(n0 + ty + 8 * i) * E + k0 + tx] = f2bf(t[tx][ty + 8 * i]);
}

// ---------------------------------------------------------------------------
// m97-style GEMM (QKV): C = A[M,K] @ BT[N,K]^T, bf16 in, fp32 acc. 128x128
// tile, BK=32, 256 thr = 4 waves 2x2; 16 MFMA + 8 ds_read_b128 per
// K-step/wave; staging via global_load_lds dwordx4. UNCHANGED from R8.
// ---------------------------------------------------------------------------
template <int PERM>
__global__ __launch_bounds__(256) void gemm128(
    const unsigned short* __restrict__ A,
    const unsigned short* __restrict__ BT,
    const float* __restrict__ bias,
    float* __restrict__ Cf,
    unsigned short* __restrict__ q_out,
    unsigned short* __restrict__ k_out,
    unsigned short* __restrict__ v_out,   // [bh][64][T] transposed
    int M, int N, int K)
{
    __shared__ __align__(16) unsigned short As[128 * 32];
    __shared__ __align__(16) unsigned short Bs[128 * 32];

    const int tid  = threadIdx.x;
    const int wave = tid >> 6;
    const int lane = tid & 63;
    const int ln15 = lane & 15;
    const int kg   = lane >> 4;
    const int bm = blockIdx.x * 128, bn = blockIdx.y * 128;
    const int wm = (wave >> 1) * 64, wn = (wave & 1) * 64;

    f32x4 acc[4][4];
#pragma unroll
    for (int i = 0; i < 4; ++i)
#pragma unroll
        for (int j = 0; j < 4; ++j) acc[i][j] = (f32x4){0.f, 0.f, 0.f, 0.f};

    const int sr = wave * 32 + (lane >> 2);
    const int sc = (lane & 3) * 8;

    for (int k0 = 0; k0 < K; k0 += 32) {
        gl_lds16(A  + (size_t)(bm + sr)      * K + k0 + sc, As + wave * 1024);
        gl_lds16(A  + (size_t)(bm + sr + 16) * K + k0 + sc, As + wave * 1024 + 512);
        gl_lds16(BT + (size_t)(bn + sr)      * K + k0 + sc, Bs + wave * 1024);
        gl_lds16(BT + (size_t)(bn + sr + 16) * K + k0 + sc, Bs + wave * 1024 + 512);
        __syncthreads();

        bf16x8 af[4], bw[4];
#pragma unroll
        for (int mt = 0; mt < 4; ++mt)
            af[mt] = *(const bf16x8*)&As[(wm + mt * 16 + ln15) * 32 + kg * 8];
#pragma unroll
        for (int nt = 0; nt < 4; ++nt)
            bw[nt] = *(const bf16x8*)&Bs[(wn + nt * 16 + ln15) * 32 + kg * 8];
        if (PERM == 0) {   // compile-time: C^T fragments (unused instantiation)
#pragma unroll
            for (int mt = 0; mt < 4; ++mt)
#pragma unroll
                for (int nt = 0; nt < 4; ++nt)
                    acc[mt][nt] = __builtin_amdgcn_mfma_f32_16x16x32_bf16(
                        bw[nt], af[mt], acc[mt][nt], 0, 0, 0);
        } else {           // compile-time: C fragments
#pragma unroll
            for (int mt = 0; mt < 4; ++mt)
#pragma unroll
                for (int nt = 0; nt < 4; ++nt)
                    acc[mt][nt] = __builtin_amdgcn_mfma_f32_16x16x32_bf16(
                        af[mt], bw[nt], acc[mt][nt], 0, 0, 0);
        }
        __syncthreads();
    }

    if (PERM == 0) {
#pragma unroll
        for (int mt = 0; mt < 4; ++mt) {
            const int row = bm + wm + mt * 16 + ln15;
#pragma unroll
            for (int nt = 0; nt < 4; ++nt) {
                const int c0 = bn + wn + nt * 16 + kg * 4;
                f32x4 bv = *(const f32x4*)(bias + c0);
                f32x4 o;
#pragma unroll
                for (int r = 0; r < 4; ++r) o[r] = acc[mt][nt][r] + bv[r];
                *(f32x4*)(Cf + (size_t)row * N + c0) = o;
            }
        }
    } else {
        const int sec = bn >> 10;
        if (sec < 2) {
            unsigned short* dst = sec == 0 ? q_out : k_out;
            const float scale = sec == 0 ? 0.125f : 1.0f;  // q pre-scale (pow2)
#pragma unroll
            for (int nt = 0; nt < 4; ++nt) {
                const int col = bn + wn + nt * 16 + ln15;
                const int h = (col >> 6) & 15, d = col & 63;
#pragma unroll
                for (int mt = 0; mt < 4; ++mt) {
#pragma unroll
                    for (int r = 0; r < 4; ++r) {
                        const int row = bm + wm + mt * 16 + kg * 4 + r;
                        const int b = row >> 11, t = row & 2047;
                        dst[((size_t)(b * 16 + h) * 2048 + t) * 64 + d] =
                            f2bf(acc[mt][nt][r] * scale);
                    }
                }
            }
        } else {
            // unswapped; pf_build over mt-pairs -> writes vT[bh][d][t] directly
#pragma unroll
            for (int nt = 0; nt < 4; ++nt) {
                const int c = bn + wn + nt * 16 + ln15;
                const int h = (c >> 6) & 15, d = c & 63;
#pragma unroll
                for (int mp = 0; mp < 2; ++mp) {
                    const int t0 = bm + wm + mp * 32 + kg * 8;
                    const int b = t0 >> 11, t = t0 & 2047;
                    bf16x8 pf = pf_build_s(acc[2 * mp][nt], acc[2 * mp + 1][nt], 1.0f);
                    *(bf16x8*)(v_out + ((size_t)(b * 16 + h) * 64 + d) * 2048 + t) = pf;
                }
            }
        }
    }
}

// ---------------------------------------------------------------------------
// out-projection GEMM, 64x64 tile: Cf = A[M,K] @ BT[N,K]^T + bias (fp32 out).
//
// R8 verified the co-residency mechanism at 128x64 (1->2 blocks/CU, -5 us).
// This round continues it: 64x64 tiles -> grid (64,16) = 1024 blocks =
// 4 blocks/CU (16 waves/CU), LDS only 8 KB. A re-reads (ao = 8 MB x16
// column-tiles) are fully L3-resident, so HBM FETCH should stay flat.
// Same verified schedule: gl_lds16 staging (one 16B round per matrix:
// 256 thr x 16B = 4 KB = 64 rows x 32 k), BK=32, single-path swapped
// mfma(bw,af) = C^T frags, f32x4 bias+store epilogue. Per wave: 32x32
// out = 2x2 frags, 4 MFMA + 4 ds_read_b128 per K-step.
// ---------------------------------------------------------------------------
__global__ __launch_bounds__(256) void gemm_op(
    const unsigned short* __restrict__ A,
    const unsigned short* __restrict__ BT,
    const float* __restrict__ bias,
    float* __restrict__ Cf,
    int M, int N, int K)
{
    __shared__ __align__(16) unsigned short As[64 * 32];
    __shared__ __align__(16) unsigned short Bs[64 * 32];

    const int tid  = threadIdx.x;
    const int wave = tid >> 6;
    const int lane = tid & 63;
    const int ln15 = lane & 15;
    const int kg   = lane >> 4;
    const int bm = blockIdx.x * 64, bn = blockIdx.y * 64;
    const int wm = (wave >> 1) * 32, wn = (wave & 1) * 32;

    f32x4 acc[2][2];
#pragma unroll
    for (int i = 0; i < 2; ++i)
#pragma unroll
        for (int j = 0; j < 2; ++j) acc[i][j] = (f32x4){0.f, 0.f, 0.f, 0.f};

    const int sr = wave * 16 + (lane >> 2);    // stage row 0..63
    const int sc = (lane & 2) ? ((lane & 3) - 2) * 8 + 16 : (lane & 3) * 8;  // == (lane&3)*8
    const int scl = (lane & 3) * 8;

    for (int k0 = 0; k0 < K; k0 += 32) {
        gl_lds16(A  + (size_t)(bm + sr) * K + k0 + scl, As + wave * 512);
        gl_lds16(BT + (size_t)(bn + sr) * K + k0 + scl, Bs + wave * 512);
        __syncthreads();

        bf16x8 af[2], bw[2];
#pragma unroll
        for (int mt = 0; mt < 2; ++mt)
            af[mt] = *(const bf16x8*)&As[(wm + mt * 16 + ln15) * 32 + kg * 8];
#pragma unroll
        for (int nt = 0; nt < 2; ++nt)
            bw[nt] = *(const bf16x8*)&Bs[(wn + nt * 16 + ln15) * 32 + kg * 8];
#pragma unroll
        for (int mt = 0; mt < 2; ++mt)
#pragma unroll
            for (int nt = 0; nt < 2; ++nt)
                acc[mt][nt] = __builtin_amdgcn_mfma_f32_16x16x32_bf16(
                    bw[nt], af[mt], acc[mt][nt], 0, 0, 0);
        __syncthreads();
    }

    // swapped: acc[mt][nt][r] = C[row=bm+wm+mt*16+ln15][col=bn+wn+nt*16+kg*4+r]
#pragma unroll
    for (int mt = 0; mt < 2; ++mt) {
        const int row = bm + wm + mt * 16 + ln15;
#pragma unroll
        for (int nt = 0; nt < 2; ++nt) {
            const int c0 = bn + wn + nt * 16 + kg * 4;
            f32x4 bv = *(const f32x4*)(bias + c0);
            f32x4 o;
#pragma unroll
            for (int r = 0; r < 4; ++r) o[r] = acc[mt][nt][r] + bv[r];
            *(f32x4*)(Cf + (size_t)row * N + c0) = o;
        }
    }
}

// mask (diagonal block) + exp + in-register transpose + row-sum accumulate
__device__ __forceinline__ void softmax_tile(
    f32x4 sr[4], bool diag, int q_loc, int kg,
    bf16x8& pf0, bf16x8& pf1, f32x4& accl, bf16x8 ones)
{
    if (diag) {
#pragma unroll
        for (int kt = 0; kt < 4; ++kt)
#pragma unroll
            for (int r = 0; r < 4; ++r)
                if (kt * 16 + kg * 4 + r > q_loc) sr[kt][r] = -1e30f;
    }
    f32x4 pe[4];
#pragma unroll
    for (int kt = 0; kt < 4; ++kt)
#pragma unroll
        for (int r = 0; r < 4; ++r) pe[kt][r] = __expf(sr[kt][r]);
    pf0 = pf_build_s(pe[0], pe[1], 1.0f);
    pf1 = pf_build_s(pe[2], pe[3], 1.0f);
    accl = __builtin_amdgcn_mfma_f32_16x16x32_bf16(pf0, ones, accl, 0, 0, 0);
    accl = __builtin_amdgcn_mfma_f32_16x16x32_bf16(pf1, ones, accl, 0, 0, 0);
}

// ---------------------------------------------------------------------------
// MFMA flash attention v6+T5 (causal). FROZEN -- exact R8-verified version.
// v9 (8-wave split) and v10 (KVBLK=128) both failed correctness with
// absmax ~1.7 and undiagnosed root cause; five structural perturbations of
// this loop have lost. Do not modify without an isolated refcheck path.
// Paired strips (sA=x, sB=31-x, 33 iters balanced); K/V staged once, shared;
// double-buffered LDS; ONE barrier/iter; register prefetch; swapped QK^T +
// in-register P transpose; s_setprio(1) around MFMA clusters.
// ---------------------------------------------------------------------------
__global__ __launch_bounds__(256) void flash_attn(
    const unsigned short* __restrict__ Q,
    const unsigned short* __restrict__ Km,
    const unsigned short* __restrict__ Vtg,
    unsigned short* __restrict__ O,
    int T, int H)
{
    __shared__ __align__(16) unsigned short Ks[2][64][72];   // [buf][key][d]
    __shared__ __align__(16) unsigned short Vs[2][64][72];   // [buf][d][key]

    const int tid  = threadIdx.x;
    const int wave = tid >> 6;
    const int lane = tid & 63;
    const int ln15 = lane & 15;
    const int kg   = lane >> 4;
    const int sA   = blockIdx.x;              // 0..15
    const int sB   = (T >> 6) - 1 - sA;       // 31..16
    const int kmax = sB;
    const int bh   = blockIdx.y;
    const int b    = bh >> 4, h = bh & 15;
    const size_t base  = (size_t)bh * T * 64;
    const size_t vbase = (size_t)bh * 64 * T;
    const int q_loc = wave * 16 + ln15;       // query row within strip

    bf16x8 qf[2][2];
    {
        const unsigned short* QrA = Q + base + (size_t)(sA * 64 + q_loc) * 64;
        const unsigned short* QrB = Q + base + (size_t)(sB * 64 + q_loc) * 64;
        qf[0][0] = *(const bf16x8*)(QrA + kg * 8);
        qf[0][1] = *(const bf16x8*)(QrA + 32 + kg * 8);
        qf[1][0] = *(const bf16x8*)(QrB + kg * 8);
        qf[1][1] = *(const bf16x8*)(QrB + 32 + kg * 8);
    }

    bf16x8 ones;
    {
        const short o = (ln15 == 0) ? (short)0x3F80 : (short)0;
#pragma unroll
        for (int j = 0; j < 8; ++j) ones[j] = o;
    }

    f32x4 o_acc[2][4];
#pragma unroll
    for (int s = 0; s < 2; ++s)
#pragma unroll
        for (int dt = 0; dt < 4; ++dt) o_acc[s][dt] = (f32x4){0.f, 0.f, 0.f, 0.f};
    f32x4 acc_l[2] = {(f32x4){0.f, 0.f, 0.f, 0.f}, (f32x4){0.f, 0.f, 0.f, 0.f}};

    const int sky = tid >> 3;             // 0..31
    const int sd  = (tid & 7) * 8;

    bf16x8 pk0, pk1, pv0, pv1;
    pk0 = *(const bf16x8*)(Km + base + (size_t)sky * 64 + sd);
    pk1 = *(const bf16x8*)(Km + base + (size_t)(sky + 32) * 64 + sd);
    pv0 = *(const bf16x8*)(Vtg + vbase + (size_t)sky * T + sd);
    pv1 = *(const bf16x8*)(Vtg + vbase + (size_t)(sky + 32) * T + sd);

    for (int kb = 0; kb <= kmax; ++kb) {
        const int bufi = kb & 1;
        *(bf16x8*)&Ks[bufi][sky][sd]      = pk0;
        *(bf16x8*)&Ks[bufi][sky + 32][sd] = pk1;
        *(bf16x8*)&Vs[bufi][sky][sd]      = pv0;
        *(bf16x8*)&Vs[bufi][sky + 32][sd] = pv1;
        if (kb < kmax) {
            const int kn = (kb + 1) * 64;
            pk0 = *(const bf16x8*)(Km + base + (size_t)(kn + sky) * 64 + sd);
            pk1 = *(const bf16x8*)(Km + base + (size_t)(kn + sky + 32) * 64 + sd);
            pv0 = *(const bf16x8*)(Vtg + vbase + (size_t)sky * T + kn + sd);
            pv1 = *(const bf16x8*)(Vtg + vbase + (size_t)(sky + 32) * T + kn + sd);
        }
        __syncthreads();

        const bool doA = (kb <= sA);

        f32x4 srB[4], srA[4];
        __builtin_amdgcn_s_setprio(1);
#pragma unroll
        for (int kt = 0; kt < 4; ++kt) {
            bf16x8 kf0 = *(const bf16x8*)&Ks[bufi][kt * 16 + ln15][kg * 8];
            bf16x8 kf1 = *(const bf16x8*)&Ks[bufi][kt * 16 + ln15][32 + kg * 8];
            f32x4 a = (f32x4){0.f, 0.f, 0.f, 0.f};
            a = __builtin_amdgcn_mfma_f32_16x16x32_bf16(kf0, qf[1][0], a, 0, 0, 0);
            a = __builtin_amdgcn_mfma_f32_16x16x32_bf16(kf1, qf[1][1], a, 0, 0, 0);
            srB[kt] = a;
            if (doA) {
                f32x4 c = (f32x4){0.f, 0.f, 0.f, 0.f};
                c = __builtin_amdgcn_mfma_f32_16x16x32_bf16(kf0, qf[0][0], c, 0, 0, 0);
                c = __builtin_amdgcn_mfma_f32_16x16x32_bf16(kf1, qf[0][1], c, 0, 0, 0);
                srA[kt] = c;
            }
        }
        __builtin_amdgcn_s_setprio(0);

        bf16x8 pfB0, pfB1, pfA0, pfA1;
        softmax_tile(srB, kb == sB, q_loc, kg, pfB0, pfB1, acc_l[1], ones);
        if (doA)
            softmax_tile(srA, kb == sA, q_loc, kg, pfA0, pfA1, acc_l[0], ones);

        __builtin_amdgcn_s_setprio(1);
#pragma unroll
        for (int dt = 0; dt < 4; ++dt) {
            bf16x8 vf0 = *(const bf16x8*)&Vs[bufi][dt * 16 + ln15][kg * 8];
            bf16x8 vf1 = *(const bf16x8*)&Vs[bufi][dt * 16 + ln15][32 + kg * 8];
            o_acc[1][dt] = __builtin_amdgcn_mfma_f32_16x16x32_bf16(pfB0, vf0, o_acc[1][dt], 0, 0, 0);
            o_acc[1][dt] = __builtin_amdgcn_mfma_f32_16x16x32_bf16(pfB1, vf1, o_acc[1][dt], 0, 0, 0);
            if (doA) {
                o_acc[0][dt] = __builtin_amdgcn_mfma_f32_16x16x32_bf16(pfA0, vf0, o_acc[0][dt], 0, 0, 0);
                o_acc[0][dt] = __builtin_amdgcn_mfma_f32_16x16x32_bf16(pfA1, vf1, o_acc[0][dt], 0, 0, 0);
            }
        }
        __builtin_amdgcn_s_setprio(0);
    }

    // normalize; l for row kg*4+r sits in lane kg*16 (col 0)
#pragma unroll
    for (int s = 0; s < 2; ++s) {
        const int qb = (s == 0 ? sA : sB) * 64;
        float inv[4];
#pragma unroll
        for (int r = 0; r < 4; ++r)
            inv[r] = 1.0f / __shfl(acc_l[s][r], lane & 48, 64);
#pragma unroll
        for (int dt = 0; dt < 4; ++dt)
#pragma unroll
            for (int r = 0; r < 4; ++r) {
                const int t = qb + wave * 16 + kg * 4 + r;
                const int d = dt * 16 + ln15;
                O[(size_t)(b * T + t) * (H * 64) + h * 64 + d] =
                    f2bf(o_acc[s][dt][r] * inv[r]);
            }
    }
}

extern "C" void kernel_launch(void* const* d_in, const int* in_sizes, int n_in,
                              void* d_out, int out_size, void* d_ws, size_t ws_size,
                              hipStream_t stream)
{
    const int B = 2, T = 2048, E = 1024, H = 16;
    const int M = B * T;  // 4096

    const float* x  = (const float*)d_in[0];
    const float* Wq = (const float*)d_in[1];
    const float* Wk = (const float*)d_in[2];
    const float* Wv = (const float*)d_in[3];
    const float* Wo = (const float*)d_in[4];
    const float* bo = (const float*)d_in[5];
    float* out = (float*)d_out;

    // workspace (bf16): xb 8MB, WqkvT 6MB, WoT 2MB, q/k/vT 8MB x3, ao 8MB
    unsigned short* xb     = (unsigned short*)d_ws;
    unsigned short* WqkvT  = xb + (size_t)M * E;            // [3072][1024]
    unsigned short* WoT    = WqkvT + (size_t)3 * E * E;     // [1024][1024]
    unsigned short* q      = WoT + (size_t)E * E;           // [BH][T][64]
    unsigned short* k      = q + (size_t)M * E;
    unsigned short* vT     = k + (size_t)M * E;             // [BH][64][T]
    unsigned short* ao     = vT + (size_t)M * E;            // [M][E]

    // fused convert + 4x weight transpose (1 launch)
    prep<<<8192, 256, 0, stream>>>(x, Wq, Wk, Wv, Wo, xb, WqkvT, WoT);

    // fused QKV projection: [4096,1024] @ [1024,3072]; V written transposed
    dim3 g1(M / 128, 3 * E / 128);
    gemm128<1><<<g1, 256, 0, stream>>>(xb, WqkvT, nullptr, nullptr, q, k, vT,
                                       M, 3 * E, E);

    // flash attention: 16 balanced strip-pair blocks x 32 bh (frozen v6+T5)
    dim3 ag(T / 128, B * H);
    flash_attn<<<ag, 256, 0, stream>>>(q, k, vT, ao, T, H);

    // out-projection: 64x64 tiles -> 1024 blocks = 4/CU (was 512 = 2/CU)
    dim3 g2(M / 64, E / 64);
    gemm_op<<<g2, 256, 0, stream>>>(ao, WoT, bo, out, M, E, E);
}

// Round 11
// 175.832 us; speedup vs baseline: 1.5029x; 1.0053x over previous
//
#include <hip/hip_runtime.h>
#include <hip/hip_bf16.h>

typedef __attribute__((ext_vector_type(8))) short bf16x8;
typedef __attribute__((ext_vector_type(4))) float f32x4;
typedef __attribute__((ext_vector_type(4))) unsigned short u16x4;

__device__ __forceinline__ unsigned short f2bf(float f) {
    union { float f; unsigned int i; } x; x.f = f;
    unsigned int lsb = (x.i >> 16) & 1u;
    x.i += 0x7fffu + lsb;  // round-to-nearest-even
    return (unsigned short)(x.i >> 16);
}

// async global->LDS DMA, 16B per lane; lds ptr wave-uniform, HW adds lane*16
__device__ __forceinline__ void gl_lds16(const unsigned short* g, unsigned short* l) {
    __builtin_amdgcn_global_load_lds(
        (const __attribute__((address_space(1))) void*)g,
        (__attribute__((address_space(3))) void*)l, 16, 0, 0);
}

__device__ __forceinline__ unsigned int cvt_pk_bf16(float lo, float hi) {
    unsigned int d;
    asm("v_cvt_pk_bf16_f32 %0, %1, %2" : "=v"(d) : "v"(lo), "v"(hi));
    return d;
}

// In-register 16x32 C-fragment transpose -> A-frag/store layout (attn-verified).
// Input: pa = C-frag rows 0..15 of a 32-row span (per-lane row=kg*4+r, col=ln15),
//        pb = rows 16..31. Output: lane (kg,ln15) holds bf16 of rows kg*8..kg*8+7
// at fixed col=ln15 -> one contiguous 16B run along the row direction.
__device__ __forceinline__ bf16x8 pf_build_s(f32x4 pa, f32x4 pb, float s) {
    unsigned int E0 = cvt_pk_bf16(pa[0] * s, pa[1] * s);
    unsigned int O0 = cvt_pk_bf16(pa[2] * s, pa[3] * s);
    unsigned int E1 = cvt_pk_bf16(pb[0] * s, pb[1] * s);
    unsigned int O1 = cvt_pk_bf16(pb[2] * s, pb[3] * s);
    asm("v_permlane32_swap_b32 %0, %1" : "+v"(E0), "+v"(E1));
    asm("v_permlane32_swap_b32 %0, %1" : "+v"(O0), "+v"(O1));
    asm("v_permlane16_swap_b32 %0, %1" : "+v"(E0), "+v"(E1));
    asm("v_permlane16_swap_b32 %0, %1" : "+v"(O0), "+v"(O1));
    union { unsigned int u[4]; bf16x8 v; } r;
    r.u[0] = E0; r.u[1] = O0; r.u[2] = E1; r.u[3] = O1;
    return r.v;
}

// ---------------------------------------------------------------------------
// fused preprocessing: blocks [0,4096) = fp32->bf16 convert of x (x4 vec);
// blocks [4096,8192) = 32x32 transpose+convert of the 4 weight matrices.
// ---------------------------------------------------------------------------
__global__ __launch_bounds__(256) void prep(
    const float* __restrict__ x,
    const float* __restrict__ Wq, const float* __restrict__ Wk,
    const float* __restrict__ Wv, const float* __restrict__ Wo,
    unsigned short* __restrict__ xb,
    unsigned short* __restrict__ WqkvT, unsigned short* __restrict__ WoT)
{
    const int E = 1024;
    const int bid = blockIdx.x;
    __shared__ float t[32][33];

    if (bid < 4096) {                       // x convert: 4096*256*4 = 4M elems
        int i = bid * 256 + threadIdx.x;
        f32x4 v = ((const f32x4*)x)[i];
        u16x4 o;
#pragma unroll
        for (int j = 0; j < 4; ++j) o[j] = f2bf(v[j]);
        ((u16x4*)xb)[i] = o;
        return;
    }
    const int r = bid - 4096;
    const int which = r >> 10;              // 0..3 : Wq,Wk,Wv,Wo
    const int sub = r & 1023;
    const float* src = which == 0 ? Wq : which == 1 ? Wk : which == 2 ? Wv : Wo;
    unsigned short* dst = which == 3 ? WoT : WqkvT + (size_t)which * E * E;

    const int tx = threadIdx.x & 31, ty = threadIdx.x >> 5;  // ty 0..7
    const int n0 = (sub & 31) * 32, k0 = (sub >> 5) * 32;
#pragma unroll
    for (int i = 0; i < 4; ++i)
        t[ty + 8 * i][tx] = src[(size_t)(k0 + ty + 8 * i) * E + n0 + tx];
    __syncthreads();
#pragma unroll
    for (int i = 0; i < 4; ++i)
        dst[(size_t)(n0 + ty + 8 * i) * E + k0 + tx] = f2bf(t[tx][ty + 8 * i]);
}

// ---------------------------------------------------------------------------
// m97-style GEMM (QKV): C = A[M,K] @ BT[N,K]^T, bf16 in, fp32 acc. 128x128
// tile, BK=32, 256 thr = 4 waves 2x2; 16 MFMA + 8 ds_read_b128 per
// K-step/wave; staging via global_load_lds dwordx4. UNCHANGED from R8/R10.
// ---------------------------------------------------------------------------
template <int PERM>
__global__ __launch_bounds__(256) void gemm128(
    const unsigned short* __restrict__ A,
    const unsigned short* __restrict__ BT,
    const float* __restrict__ bias,
    float* __restrict__ Cf,
    unsigned short* __restrict__ q_out,
    unsigned short* __restrict__ k_out,
    unsigned short* __restrict__ v_out,   // [bh][64][T] transposed
    int M, int N, int K)
{
    __shared__ __align__(16) unsigned short As[128 * 32];
    __shared__ __align__(16) unsigned short Bs[128 * 32];

    const int tid  = threadIdx.x;
    const int wave = tid >> 6;
    const int lane = tid & 63;
    const int ln15 = lane & 15;
    const int kg   = lane >> 4;
    const int bm = blockIdx.x * 128, bn = blockIdx.y * 128;
    const int wm = (wave >> 1) * 64, wn = (wave & 1) * 64;

    f32x4 acc[4][4];
#pragma unroll
    for (int i = 0; i < 4; ++i)
#pragma unroll
        for (int j = 0; j < 4; ++j) acc[i][j] = (f32x4){0.f, 0.f, 0.f, 0.f};

    const int sr = wave * 32 + (lane >> 2);
    const int sc = (lane & 3) * 8;

    for (int k0 = 0; k0 < K; k0 += 32) {
        gl_lds16(A  + (size_t)(bm + sr)      * K + k0 + sc, As + wave * 1024);
        gl_lds16(A  + (size_t)(bm + sr + 16) * K + k0 + sc, As + wave * 1024 + 512);
        gl_lds16(BT + (size_t)(bn + sr)      * K + k0 + sc, Bs + wave * 1024);
        gl_lds16(BT + (size_t)(bn + sr + 16) * K + k0 + sc, Bs + wave * 1024 + 512);
        __syncthreads();

        bf16x8 af[4], bw[4];
#pragma unroll
        for (int mt = 0; mt < 4; ++mt)
            af[mt] = *(const bf16x8*)&As[(wm + mt * 16 + ln15) * 32 + kg * 8];
#pragma unroll
        for (int nt = 0; nt < 4; ++nt)
            bw[nt] = *(const bf16x8*)&Bs[(wn + nt * 16 + ln15) * 32 + kg * 8];
        if (PERM == 0) {   // compile-time: C^T fragments (unused instantiation)
#pragma unroll
            for (int mt = 0; mt < 4; ++mt)
#pragma unroll
                for (int nt = 0; nt < 4; ++nt)
                    acc[mt][nt] = __builtin_amdgcn_mfma_f32_16x16x32_bf16(
                        bw[nt], af[mt], acc[mt][nt], 0, 0, 0);
        } else {           // compile-time: C fragments
#pragma unroll
            for (int mt = 0; mt < 4; ++mt)
#pragma unroll
                for (int nt = 0; nt < 4; ++nt)
                    acc[mt][nt] = __builtin_amdgcn_mfma_f32_16x16x32_bf16(
                        af[mt], bw[nt], acc[mt][nt], 0, 0, 0);
        }
        __syncthreads();
    }

    if (PERM == 0) {
#pragma unroll
        for (int mt = 0; mt < 4; ++mt) {
            const int row = bm + wm + mt * 16 + ln15;
#pragma unroll
            for (int nt = 0; nt < 4; ++nt) {
                const int c0 = bn + wn + nt * 16 + kg * 4;
                f32x4 bv = *(const f32x4*)(bias + c0);
                f32x4 o;
#pragma unroll
                for (int r = 0; r < 4; ++r) o[r] = acc[mt][nt][r] + bv[r];
                *(f32x4*)(Cf + (size_t)row * N + c0) = o;
            }
        }
    } else {
        const int sec = bn >> 10;
        if (sec < 2) {
            unsigned short* dst = sec == 0 ? q_out : k_out;
            const float scale = sec == 0 ? 0.125f : 1.0f;  // q pre-scale (pow2)
#pragma unroll
            for (int nt = 0; nt < 4; ++nt) {
                const int col = bn + wn + nt * 16 + ln15;
                const int h = (col >> 6) & 15, d = col & 63;
#pragma unroll
                for (int mt = 0; mt < 4; ++mt) {
#pragma unroll
                    for (int r = 0; r < 4; ++r) {
                        const int row = bm + wm + mt * 16 + kg * 4 + r;
                        const int b = row >> 11, t = row & 2047;
                        dst[((size_t)(b * 16 + h) * 2048 + t) * 64 + d] =
                            f2bf(acc[mt][nt][r] * scale);
                    }
                }
            }
        } else {
            // unswapped; pf_build over mt-pairs -> writes vT[bh][d][t] directly
#pragma unroll
            for (int nt = 0; nt < 4; ++nt) {
                const int c = bn + wn + nt * 16 + ln15;
                const int h = (c >> 6) & 15, d = c & 63;
#pragma unroll
                for (int mp = 0; mp < 2; ++mp) {
                    const int t0 = bm + wm + mp * 32 + kg * 8;
                    const int b = t0 >> 11, t = t0 & 2047;
                    bf16x8 pf = pf_build_s(acc[2 * mp][nt], acc[2 * mp + 1][nt], 1.0f);
                    *(bf16x8*)(v_out + ((size_t)(b * 16 + h) * 64 + d) * 2048 + t) = pf;
                }
            }
        }
    }
}

// ---------------------------------------------------------------------------
// out-projection GEMM, 64x64 tile (1024 blocks = 4/CU). UNCHANGED from R10.
// ---------------------------------------------------------------------------
__global__ __launch_bounds__(256) void gemm_op(
    const unsigned short* __restrict__ A,
    const unsigned short* __restrict__ BT,
    const float* __restrict__ bias,
    float* __restrict__ Cf,
    int M, int N, int K)
{
    __shared__ __align__(16) unsigned short As[64 * 32];
    __shared__ __align__(16) unsigned short Bs[64 * 32];

    const int tid  = threadIdx.x;
    const int wave = tid >> 6;
    const int lane = tid & 63;
    const int ln15 = lane & 15;
    const int kg   = lane >> 4;
    const int bm = blockIdx.x * 64, bn = blockIdx.y * 64;
    const int wm = (wave >> 1) * 32, wn = (wave & 1) * 32;

    f32x4 acc[2][2];
#pragma unroll
    for (int i = 0; i < 2; ++i)
#pragma unroll
        for (int j = 0; j < 2; ++j) acc[i][j] = (f32x4){0.f, 0.f, 0.f, 0.f};

    const int sr = wave * 16 + (lane >> 2);    // stage row 0..63
    const int sc = (lane & 2) ? ((lane & 3) - 2) * 8 + 16 : (lane & 3) * 8;  // == (lane&3)*8
    const int scl = (lane & 3) * 8;

    for (int k0 = 0; k0 < K; k0 += 32) {
        gl_lds16(A  + (size_t)(bm + sr) * K + k0 + scl, As + wave * 512);
        gl_lds16(BT + (size_t)(bn + sr) * K + k0 + scl, Bs + wave * 512);
        __syncthreads();

        bf16x8 af[2], bw[2];
#pragma unroll
        for (int mt = 0; mt < 2; ++mt)
            af[mt] = *(const bf16x8*)&As[(wm + mt * 16 + ln15) * 32 + kg * 8];
#pragma unroll
        for (int nt = 0; nt < 2; ++nt)
            bw[nt] = *(const bf16x8*)&Bs[(wn + nt * 16 + ln15) * 32 + kg * 8];
#pragma unroll
        for (int mt = 0; mt < 2; ++mt)
#pragma unroll
            for (int nt = 0; nt < 2; ++nt)
                acc[mt][nt] = __builtin_amdgcn_mfma_f32_16x16x32_bf16(
                    bw[nt], af[mt], acc[mt][nt], 0, 0, 0);
        __syncthreads();
    }

    // swapped: acc[mt][nt][r] = C[row=bm+wm+mt*16+ln15][col=bn+wn+nt*16+kg*4+r]
#pragma unroll
    for (int mt = 0; mt < 2; ++mt) {
        const int row = bm + wm + mt * 16 + ln15;
#pragma unroll
        for (int nt = 0; nt < 2; ++nt) {
            const int c0 = bn + wn + nt * 16 + kg * 4;
            f32x4 bv = *(const f32x4*)(bias + c0);
            f32x4 o;
#pragma unroll
            for (int r = 0; r < 4; ++r) o[r] = acc[mt][nt][r] + bv[r];
            *(f32x4*)(Cf + (size_t)row * N + c0) = o;
        }
    }
}

// mask (diagonal block) + exp + in-register transpose + row-sum accumulate
__device__ __forceinline__ void softmax_tile(
    f32x4 sr[4], bool diag, int q_loc, int kg,
    bf16x8& pf0, bf16x8& pf1, f32x4& accl, bf16x8 ones)
{
    if (diag) {
#pragma unroll
        for (int kt = 0; kt < 4; ++kt)
#pragma unroll
            for (int r = 0; r < 4; ++r)
                if (kt * 16 + kg * 4 + r > q_loc) sr[kt][r] = -1e30f;
    }
    f32x4 pe[4];
#pragma unroll
    for (int kt = 0; kt < 4; ++kt)
#pragma unroll
        for (int r = 0; r < 4; ++r) pe[kt][r] = __expf(sr[kt][r]);
    pf0 = pf_build_s(pe[0], pe[1], 1.0f);
    pf1 = pf_build_s(pe[2], pe[3], 1.0f);
    accl = __builtin_amdgcn_mfma_f32_16x16x32_bf16(pf0, ones, accl, 0, 0, 0);
    accl = __builtin_amdgcn_mfma_f32_16x16x32_bf16(pf1, ones, accl, 0, 0, 0);
}

// ---------------------------------------------------------------------------
// MFMA flash attention v6+T5 (causal). LOOP FROZEN -- exact R8/R10-verified
// iteration (v9/v10 structural edits both failed correctness, undiagnosed).
//
// R11 change is INDEXING ONLY: XCD-locality block remap. Default x-major
// dispatch spreads the 16 blocks sharing one bh (one 512 KB K/V set) across
// all 8 XCDs -> every XCD's L2 pulls every head's K/V; prefetch loads pay
// L3/HBM latency inside the per-iteration drain (attn FETCH 55 MB vs 24
// ideal). Remap (bijective, 512 = 8 x 64): flat%8 = XCD slot -> all 16
// same-bh blocks on one XCD; 4 heads/XCD = 2 MB K/V < 4 MB L2. Per-XCD
// work stays perfectly balanced (every strip-pair = 33 iters). Pure index
// permutation; dispatch->XCD mapping is a perf heuristic only (guide §1).
// ---------------------------------------------------------------------------
__global__ __launch_bounds__(256) void flash_attn(
    const unsigned short* __restrict__ Q,
    const unsigned short* __restrict__ Km,
    const unsigned short* __restrict__ Vtg,
    unsigned short* __restrict__ O,
    int T, int H)
{
    __shared__ __align__(16) unsigned short Ks[2][64][72];   // [buf][key][d]
    __shared__ __align__(16) unsigned short Vs[2][64][72];   // [buf][d][key]

    const int tid  = threadIdx.x;
    const int wave = tid >> 6;
    const int lane = tid & 63;
    const int ln15 = lane & 15;
    const int kg   = lane >> 4;

    // XCD-locality remap: flat -> (xcd, slot); 4 heads per XCD, 16 strips each
    const int flat = blockIdx.y * gridDim.x + blockIdx.x;   // 0..511
    const int xcd  = flat & 7;
    const int slot = flat >> 3;                             // 0..63
    const int bh   = xcd * 4 + (slot >> 4);                 // 0..31
    const int sA   = slot & 15;                             // 0..15

    const int sB   = (T >> 6) - 1 - sA;       // 31..16
    const int kmax = sB;
    const int b    = bh >> 4, h = bh & 15;
    const size_t base  = (size_t)bh * T * 64;
    const size_t vbase = (size_t)bh * 64 * T;
    const int q_loc = wave * 16 + ln15;       // query row within strip

    bf16x8 qf[2][2];
    {
        const unsigned short* QrA = Q + base + (size_t)(sA * 64 + q_loc) * 64;
        const unsigned short* QrB = Q + base + (size_t)(sB * 64 + q_loc) * 64;
        qf[0][0] = *(const bf16x8*)(QrA + kg * 8);
        qf[0][1] = *(const bf16x8*)(QrA + 32 + kg * 8);
        qf[1][0] = *(const bf16x8*)(QrB + kg * 8);
        qf[1][1] = *(const bf16x8*)(QrB + 32 + kg * 8);
    }

    bf16x8 ones;
    {
        const short o = (ln15 == 0) ? (short)0x3F80 : (short)0;
#pragma unroll
        for (int j = 0; j < 8; ++j) ones[j] = o;
    }

    f32x4 o_acc[2][4];
#pragma unroll
    for (int s = 0; s < 2; ++s)
#pragma unroll
        for (int dt = 0; dt < 4; ++dt) o_acc[s][dt] = (f32x4){0.f, 0.f, 0.f, 0.f};
    f32x4 acc_l[2] = {(f32x4){0.f, 0.f, 0.f, 0.f}, (f32x4){0.f, 0.f, 0.f, 0.f}};

    const int sky = tid >> 3;             // 0..31
    const int sd  = (tid & 7) * 8;

    bf16x8 pk0, pk1, pv0, pv1;
    pk0 = *(const bf16x8*)(Km + base + (size_t)sky * 64 + sd);
    pk1 = *(const bf16x8*)(Km + base + (size_t)(sky + 32) * 64 + sd);
    pv0 = *(const bf16x8*)(Vtg + vbase + (size_t)sky * T + sd);
    pv1 = *(const bf16x8*)(Vtg + vbase + (size_t)(sky + 32) * T + sd);

    for (int kb = 0; kb <= kmax; ++kb) {
        const int bufi = kb & 1;
        *(bf16x8*)&Ks[bufi][sky][sd]      = pk0;
        *(bf16x8*)&Ks[bufi][sky + 32][sd] = pk1;
        *(bf16x8*)&Vs[bufi][sky][sd]      = pv0;
        *(bf16x8*)&Vs[bufi][sky + 32][sd] = pv1;
        if (kb < kmax) {
            const int kn = (kb + 1) * 64;
            pk0 = *(const bf16x8*)(Km + base + (size_t)(kn + sky) * 64 + sd);
            pk1 = *(const bf16x8*)(Km + base + (size_t)(kn + sky + 32) * 64 + sd);
            pv0 = *(const bf16x8*)(Vtg + vbase + (size_t)sky * T + kn + sd);
            pv1 = *(const bf16x8*)(Vtg + vbase + (size_t)(sky + 32) * T + kn + sd);
        }
        __syncthreads();

        const bool doA = (kb <= sA);

        f32x4 srB[4], srA[4];
        __builtin_amdgcn_s_setprio(1);
#pragma unroll
        for (int kt = 0; kt < 4; ++kt) {
            bf16x8 kf0 = *(const bf16x8*)&Ks[bufi][kt * 16 + ln15][kg * 8];
            bf16x8 kf1 = *(const bf16x8*)&Ks[bufi][kt * 16 + ln15][32 + kg * 8];
            f32x4 a = (f32x4){0.f, 0.f, 0.f, 0.f};
            a = __builtin_amdgcn_mfma_f32_16x16x32_bf16(kf0, qf[1][0], a, 0, 0, 0);
            a = __builtin_amdgcn_mfma_f32_16x16x32_bf16(kf1, qf[1][1], a, 0, 0, 0);
            srB[kt] = a;
            if (doA) {
                f32x4 c = (f32x4){0.f, 0.f, 0.f, 0.f};
                c = __builtin_amdgcn_mfma_f32_16x16x32_bf16(kf0, qf[0][0], c, 0, 0, 0);
                c = __builtin_amdgcn_mfma_f32_16x16x32_bf16(kf1, qf[0][1], c, 0, 0, 0);
                srA[kt] = c;
            }
        }
        __builtin_amdgcn_s_setprio(0);

        bf16x8 pfB0, pfB1, pfA0, pfA1;
        softmax_tile(srB, kb == sB, q_loc, kg, pfB0, pfB1, acc_l[1], ones);
        if (doA)
            softmax_tile(srA, kb == sA, q_loc, kg, pfA0, pfA1, acc_l[0], ones);

        __builtin_amdgcn_s_setprio(1);
#pragma unroll
        for (int dt = 0; dt < 4; ++dt) {
            bf16x8 vf0 = *(const bf16x8*)&Vs[bufi][dt * 16 + ln15][kg * 8];
            bf16x8 vf1 = *(const bf16x8*)&Vs[bufi][dt * 16 + ln15][32 + kg * 8];
            o_acc[1][dt] = __builtin_amdgcn_mfma_f32_16x16x32_bf16(pfB0, vf0, o_acc[1][dt], 0, 0, 0);
            o_acc[1][dt] = __builtin_amdgcn_mfma_f32_16x16x32_bf16(pfB1, vf1, o_acc[1][dt], 0, 0, 0);
            if (doA) {
                o_acc[0][dt] = __builtin_amdgcn_mfma_f32_16x16x32_bf16(pfA0, vf0, o_acc[0][dt], 0, 0, 0);
                o_acc[0][dt] = __builtin_amdgcn_mfma_f32_16x16x32_bf16(pfA1, vf1, o_acc[0][dt], 0, 0, 0);
            }
        }
        __builtin_amdgcn_s_setprio(0);
    }

    // normalize; l for row kg*4+r sits in lane kg*16 (col 0)
#pragma unroll
    for (int s = 0; s < 2; ++s) {
        const int qb = (s == 0 ? sA : sB) * 64;
        float inv[4];
#pragma unroll
        for (int r = 0; r < 4; ++r)
            inv[r] = 1.0f / __shfl(acc_l[s][r], lane & 48, 64);
#pragma unroll
        for (int dt = 0; dt < 4; ++dt)
#pragma unroll
            for (int r = 0; r < 4; ++r) {
                const int t = qb + wave * 16 + kg * 4 + r;
                const int d = dt * 16 + ln15;
                O[(size_t)(b * T + t) * (H * 64) + h * 64 + d] =
                    f2bf(o_acc[s][dt][r] * inv[r]);
            }
    }
}

extern "C" void kernel_launch(void* const* d_in, const int* in_sizes, int n_in,
                              void* d_out, int out_size, void* d_ws, size_t ws_size,
                              hipStream_t stream)
{
    const int B = 2, T = 2048, E = 1024, H = 16;
    const int M = B * T;  // 4096

    const float* x  = (const float*)d_in[0];
    const float* Wq = (const float*)d_in[1];
    const float* Wk = (const float*)d_in[2];
    const float* Wv = (const float*)d_in[3];
    const float* Wo = (const float*)d_in[4];
    const float* bo = (const float*)d_in[5];
    float* out = (float*)d_out;

    // workspace (bf16): xb 8MB, WqkvT 6MB, WoT 2MB, q/k/vT 8MB x3, ao 8MB
    unsigned short* xb     = (unsigned short*)d_ws;
    unsigned short* WqkvT  = xb + (size_t)M * E;            // [3072][1024]
    unsigned short* WoT    = WqkvT + (size_t)3 * E * E;     // [1024][1024]
    unsigned short* q      = WoT + (size_t)E * E;           // [BH][T][64]
    unsigned short* k      = q + (size_t)M * E;
    unsigned short* vT     = k + (size_t)M * E;             // [BH][64][T]
    unsigned short* ao     = vT + (size_t)M * E;            // [M][E]

    // fused convert + 4x weight transpose (1 launch)
    prep<<<8192, 256, 0, stream>>>(x, Wq, Wk, Wv, Wo, xb, WqkvT, WoT);

    // fused QKV projection: [4096,1024] @ [1024,3072]; V written transposed
    dim3 g1(M / 128, 3 * E / 128);
    gemm128<1><<<g1, 256, 0, stream>>>(xb, WqkvT, nullptr, nullptr, q, k, vT,
                                       M, 3 * E, E);

    // flash attention: 512 blocks, XCD-locality remapped (frozen v6+T5 loop)
    dim3 ag(T / 128, B * H);
    flash_attn<<<ag, 256, 0, stream>>>(q, k, vT, ao, T, H);

    // out-projection: 64x64 tiles -> 1024 blocks = 4/CU
    dim3 g2(M / 64, E / 64);
    gemm_op<<<g2, 256, 0, stream>>>(ao, WoT, bo, out, M, E, E);
}